// Round 2
// baseline (1763.383 us; speedup 1.0000x reference)
//
#include <hip/hip_runtime.h>
#include <hip/hip_fp16.h>
#include <math.h>

#define IN_DIM 256
#define OUT_DIM 64
#define BROWS 256             // nodes per bucket
#define HIST_EDGES 8192       // edges per hist block
#define SC_THREADS 512
#define SC_EPB 16
#define SC_EDGES (SC_THREADS * SC_EPB)  // 8192 edges per scatter block
#define BM 128                // gemm rows per block
#define KC 32                 // gemm k-chunk
#define HS_LD 33              // padded leading dim of h tile in LDS
#define AGG_THREADS 512
#define AGG_EPW 8             // edges per wave per iteration (MLP depth)

// ---------------------------------------------------------------------------
// K1: dst-bucket histogram (LDS-privatized) + out_deg via direct global
// atomics (L2-resident 400 KB; replaces the whole src-side multisplit).
// ---------------------------------------------------------------------------
__global__ void __launch_bounds__(256) hist_kernel(
        const int* __restrict__ src, const int* __restrict__ dst,
        int* __restrict__ hist, int* __restrict__ out_deg,
        int n_edges, int nb) {
    __shared__ int lhd[512];
    for (int i = threadIdx.x; i < nb; i += 256) lhd[i] = 0;
    __syncthreads();
    const int base = blockIdx.x * HIST_EDGES;
    for (int i = threadIdx.x; i < HIST_EDGES; i += 256) {
        int e = base + i;
        if (e < n_edges) {
            atomicAdd(&lhd[dst[e] >> 8], 1);
            atomicAdd(&out_deg[src[e]], 1);
        }
    }
    __syncthreads();
    for (int i = threadIdx.x; i < nb; i += 256)
        if (lhd[i]) atomicAdd(&hist[i], lhd[i]);
}

// ---------------------------------------------------------------------------
// K2: parallel exclusive scan of the dst-bucket histogram (one block,
// Hillis-Steele in LDS; nb = 391 <= 512). Replaces the serial 1-thread loop.
// ---------------------------------------------------------------------------
__global__ void __launch_bounds__(512) scan_kernel(
        const int* __restrict__ hist, int* __restrict__ dbase,
        int* __restrict__ dcursor, int nb) {
    __shared__ int sc[512];
    const int t = threadIdx.x;
    int v = (t < nb) ? hist[t] : 0;
    sc[t] = v;
    __syncthreads();
    #pragma unroll
    for (int d = 1; d < 512; d <<= 1) {
        int tv = (t >= d) ? sc[t - d] : 0;
        __syncthreads();
        sc[t] += tv;
        __syncthreads();
    }
    const int excl = sc[t] - v;          // exclusive prefix (v==0 for t>=nb)
    if (t < nb) { dbase[t] = excl; dcursor[t] = excl; }
    if (t == nb) dbase[t] = excl;        // total edge count
}

// ---------------------------------------------------------------------------
// K3: dst-only multisplit. Packed (src<<8 | dst&255) into dst-bucket
// segments. Segment reservation = one global atomic per (block,bucket).
// ---------------------------------------------------------------------------
__global__ void __launch_bounds__(SC_THREADS) scatter_kernel(
        const int* __restrict__ src, const int* __restrict__ dst,
        int* __restrict__ dcursor, unsigned* __restrict__ pairs,
        int n_edges, int nb) {
    __shared__ int lhd[512];    // bucket count, then local cursor
    __shared__ int lbd[512];    // bucket reserved global base
    const int t = threadIdx.x;
    for (int i = t; i < nb; i += SC_THREADS) lhd[i] = 0;
    __syncthreads();

    const int base = blockIdx.x * SC_EDGES;
    int s[SC_EPB], d[SC_EPB];
    #pragma unroll
    for (int i = 0; i < SC_EPB; ++i) {
        int e = base + i * SC_THREADS + t;
        if (e < n_edges) {
            s[i] = src[e];
            d[i] = dst[e];
            atomicAdd(&lhd[d[i] >> 8], 1);
        } else {
            s[i] = -1; d[i] = 0;
        }
    }
    __syncthreads();
    for (int i = t; i < nb; i += SC_THREADS) {
        int c = lhd[i];
        lbd[i] = c ? atomicAdd(&dcursor[i], c) : 0;
        lhd[i] = 0;
    }
    __syncthreads();
    #pragma unroll
    for (int i = 0; i < SC_EPB; ++i) {
        if (s[i] >= 0) {
            int bkt = d[i] >> 8;
            int pos = lbd[bkt] + atomicAdd(&lhd[bkt], 1);
            pairs[pos] = ((unsigned)s[i] << 8) | (unsigned)(d[i] & 255);
        }
    }
}

// ---------------------------------------------------------------------------
// K4: register-tiled GEMM. m[row] = (h[row] @ W) * rsqrt(max(out_deg,1)),
// stored as FP16 (halves the random-gather bytes in K5).
// 256 threads, 128x64 tile, 8x4 acc per thread; ~25 KB LDS.
// ---------------------------------------------------------------------------
__global__ void __launch_bounds__(256) gemm_kernel(
        const float* __restrict__ h, const float* __restrict__ W,
        const int* __restrict__ out_deg, __half* __restrict__ m, int n_nodes) {
    __shared__ float hs[BM * HS_LD];       // 16.9 KB
    __shared__ float Ws[KC * OUT_DIM];     // 8 KB

    const int t = threadIdx.x;
    const int c = t & 15;   // col group (4 cols)
    const int g = t >> 4;   // row group (8 rows)
    const int rowBase = blockIdx.x * BM;

    float acc[8][4];
    #pragma unroll
    for (int i = 0; i < 8; ++i)
        #pragma unroll
        for (int j = 0; j < 4; ++j) acc[i][j] = 0.f;

    for (int kc = 0; kc < IN_DIM / KC; ++kc) {
        __syncthreads();
        #pragma unroll
        for (int i = 0; i < 4; ++i) {
            int idx = t + 256 * i;
            int row = idx >> 3;
            int seg = idx & 7;
            int grow = rowBase + row;
            float4 v = make_float4(0.f, 0.f, 0.f, 0.f);
            if (grow < n_nodes)
                v = *(const float4*)(h + (size_t)grow * IN_DIM + kc * KC + seg * 4);
            float* dp = &hs[row * HS_LD + seg * 4];
            dp[0] = v.x; dp[1] = v.y; dp[2] = v.z; dp[3] = v.w;
        }
        {
            const float4* Wg = (const float4*)(W + kc * KC * OUT_DIM);
            float4* Wl = (float4*)Ws;
            Wl[t] = Wg[t];
            Wl[t + 256] = Wg[t + 256];
        }
        __syncthreads();

        #pragma unroll 4
        for (int kk = 0; kk < KC; ++kk) {
            float4 bv = *(const float4*)&Ws[kk * OUT_DIM + c * 4];
            #pragma unroll
            for (int i = 0; i < 8; ++i) {
                float a = hs[(g * 8 + i) * HS_LD + kk];
                acc[i][0] += a * bv.x;
                acc[i][1] += a * bv.y;
                acc[i][2] += a * bv.z;
                acc[i][3] += a * bv.w;
            }
        }
    }

    #pragma unroll
    for (int i = 0; i < 8; ++i) {
        int row = rowBase + g * 8 + i;
        if (row < n_nodes) {
            float nr = rsqrtf(fmaxf((float)out_deg[row], 1.0f));
            union { __half2 h2[2]; uint2 u; } pk;
            pk.h2[0] = __floats2half2_rn(acc[i][0] * nr, acc[i][1] * nr);
            pk.h2[1] = __floats2half2_rn(acc[i][2] * nr, acc[i][3] * nr);
            *(uint2*)(m + (size_t)row * OUT_DIM + c * 4) = pk.u;
        }
    }
}

// ---------------------------------------------------------------------------
// K5: fused bucket aggregate. One block per dst-bucket; 64 KB fp32 LDS
// accumulator (256 rows x 64 cols). Streams the bucket's packed pairs,
// gathers m[src] rows (fp16, 128 B per wave), ds_add_f32 into LDS
// (bank = lane%32 -> conflict-free), counts in-degree in LDS, then fused
// norm_dst + bias + log_softmax epilogue. Replaces bucket2csr + gather:
// no csr_src / row_start traffic at all.
// ---------------------------------------------------------------------------
__global__ void __launch_bounds__(AGG_THREADS) agg_kernel(
        const unsigned* __restrict__ pairs, const int* __restrict__ dbase,
        const __half* __restrict__ m, const float* __restrict__ b,
        float* __restrict__ out, int n_nodes) {
    __shared__ float acc[BROWS * OUT_DIM];   // 64 KB
    __shared__ int cnt[BROWS];               // 1 KB

    const int t = threadIdx.x;
    const int wave = t >> 6;
    const int lane = t & 63;
    const int beg = dbase[blockIdx.x];
    const int end = dbase[blockIdx.x + 1];
    const int rowBase = blockIdx.x * BROWS;

    #pragma unroll
    for (int i = t; i < BROWS * OUT_DIM / 4; i += AGG_THREADS)
        ((float4*)acc)[i] = make_float4(0.f, 0.f, 0.f, 0.f);
    for (int i = t; i < BROWS; i += AGG_THREADS) cnt[i] = 0;
    __syncthreads();

    // 8 waves x AGG_EPW edges per iteration; AGG_EPW outstanding 128 B
    // gathers per wave hide HBM latency at 16 waves/CU (LDS-capped occ).
    for (int e = beg + wave * AGG_EPW; e < end; e += 8 * AGG_EPW) {
        const int nrem = end - e;
        unsigned p[AGG_EPW];
        float v[AGG_EPW];
        #pragma unroll
        for (int k = 0; k < AGG_EPW; ++k)
            p[k] = (k < nrem) ? pairs[e + k] : 0u;
        #pragma unroll
        for (int k = 0; k < AGG_EPW; ++k)
            if (k < nrem)
                v[k] = __half2float(m[(size_t)(p[k] >> 8) * OUT_DIM + lane]);
        #pragma unroll
        for (int k = 0; k < AGG_EPW; ++k)
            if (k < nrem) {
                int dr = (int)(p[k] & 255u);
                atomicAdd(&acc[dr * OUT_DIM + lane], v[k]);
                if (lane == 0) atomicAdd(&cnt[dr], 1);
            }
    }
    __syncthreads();

    // epilogue: 32 rows per wave, lane = class column
    for (int r = wave; r < BROWS; r += 8) {
        const int row = rowBase + r;
        if (row >= n_nodes) continue;
        float nd = rsqrtf(fmaxf((float)cnt[r], 1.0f));
        float x = acc[r * OUT_DIM + lane] * nd + b[lane];
        float mx = x;
        #pragma unroll
        for (int o = 32; o > 0; o >>= 1) mx = fmaxf(mx, __shfl_xor(mx, o, 64));
        float ex = expf(x - mx);
        float sm = ex;
        #pragma unroll
        for (int o = 32; o > 0; o >>= 1) sm += __shfl_xor(sm, o, 64);
        out[(size_t)row * OUT_DIM + lane] = x - mx - logf(sm);
    }
}

// ---------------------------------------------------------------------------
static inline size_t align16(size_t x) { return (x + 15) & ~(size_t)15; }

extern "C" void kernel_launch(void* const* d_in, const int* in_sizes, int n_in,
                              void* d_out, int out_size, void* d_ws, size_t ws_size,
                              hipStream_t stream) {
    const float* h = (const float*)d_in[0];
    const float* W = (const float*)d_in[1];
    const float* b = (const float*)d_in[2];
    const int* edges = (const int*)d_in[3];

    const int out_dim = in_sizes[2];            // 64
    const int in_dim  = in_sizes[1] / out_dim;  // 256
    const int n_nodes = in_sizes[0] / in_dim;   // 100000
    const int n_edges = in_sizes[3] / 2;        // 3200000

    const int* src = edges;
    const int* dst = edges + n_edges;

    float* out = (float*)d_out;

    const int nb = (n_nodes + BROWS - 1) / BROWS;  // 391 buckets

    // workspace carve-up (out_deg and hist kept contiguous for one memset)
    char* ws = (char*)d_ws;
    size_t off = 0;
    int* out_deg     = (int*)(ws + off); off = align16(off + (size_t)n_nodes * 4);
    int* hist        = (int*)(ws + off); off = align16(off + (size_t)nb * 4);
    int* dbase       = (int*)(ws + off); off = align16(off + (size_t)(nb + 1) * 4);
    int* dcursor     = (int*)(ws + off); off = align16(off + (size_t)nb * 4);
    __half* m        = (__half*)(ws + off); off = align16(off + (size_t)n_nodes * OUT_DIM * 2);
    unsigned* pairs  = (unsigned*)(ws + off); off = align16(off + (size_t)n_edges * 4);

    // zero out_deg + hist in one shot (they are adjacent: n_nodes*4 is
    // 16-aligned so align16 inserts no gap)
    (void)hipMemsetAsync(out_deg, 0,
                         (size_t)((char*)(hist + nb) - (char*)out_deg), stream);

    const int hist_blocks = (n_edges + HIST_EDGES - 1) / HIST_EDGES;
    const int sc_blocks   = (n_edges + SC_EDGES - 1) / SC_EDGES;

    hist_kernel<<<hist_blocks, 256, 0, stream>>>(src, dst, hist, out_deg,
                                                 n_edges, nb);
    scan_kernel<<<1, 512, 0, stream>>>(hist, dbase, dcursor, nb);
    scatter_kernel<<<sc_blocks, SC_THREADS, 0, stream>>>(
        src, dst, dcursor, pairs, n_edges, nb);

    gemm_kernel<<<(n_nodes + BM - 1) / BM, 256, 0, stream>>>(h, W, out_deg, m, n_nodes);

    agg_kernel<<<nb, AGG_THREADS, 0, stream>>>(pairs, dbase, m, b, out, n_nodes);
}

// Round 3
// 425.935 us; speedup vs baseline: 4.1400x; 4.1400x over previous
//
#include <hip/hip_runtime.h>
#include <hip/hip_fp16.h>
#include <math.h>

#define IN_DIM 256
#define OUT_DIM 64
#define BROWS 256             // nodes per bucket
#define HIST_EDGES 8192       // edges per hist block
#define SC_THREADS 512
#define SC_EPB 16
#define SC_EDGES (SC_THREADS * SC_EPB)  // 8192 edges per scatter block
#define BM 128                // gemm rows per block
#define KC 32                 // gemm k-chunk
#define HS_LD 33              // padded leading dim of h tile in LDS

// ---------------------------------------------------------------------------
// K1: dual bucket histogram (dst>>8 and src>>8), LDS-privatized, one edge
// pass, NO per-node atomics (round-2 showed global-atomic out_deg costs
// ~40+ us). hist layout: [0..nb) dst buckets, [nb..2nb) src buckets.
// ---------------------------------------------------------------------------
__global__ void __launch_bounds__(256) hist_kernel(
        const int* __restrict__ src, const int* __restrict__ dst,
        int* __restrict__ hist2, int n_edges, int nb) {
    __shared__ int lhd[512];
    __shared__ int lhs[512];
    for (int i = threadIdx.x; i < nb; i += 256) { lhd[i] = 0; lhs[i] = 0; }
    __syncthreads();
    const int base = blockIdx.x * HIST_EDGES;
    for (int i = threadIdx.x; i < HIST_EDGES; i += 256) {
        int e = base + i;
        if (e < n_edges) {
            atomicAdd(&lhd[dst[e] >> 8], 1);
            atomicAdd(&lhs[src[e] >> 8], 1);
        }
    }
    __syncthreads();
    for (int i = threadIdx.x; i < nb; i += 256) {
        if (lhd[i]) atomicAdd(&hist2[i], lhd[i]);
        if (lhs[i]) atomicAdd(&hist2[nb + i], lhs[i]);
    }
}

// ---------------------------------------------------------------------------
// K2a: parallel exclusive scans of both bucket histograms. Block 0 scans the
// dst histogram, block 1 the src histogram (Hillis-Steele in LDS; needs
// nb < 512). Replaces the serial single-thread loop (782 dependent loads).
// ---------------------------------------------------------------------------
__global__ void __launch_bounds__(512) scan2_kernel(
        const int* __restrict__ hist2,
        int* __restrict__ dbase, int* __restrict__ dcursor,
        int* __restrict__ sbase, int* __restrict__ scursor,
        int* __restrict__ row_start, int nb, int n_nodes) {
    __shared__ int sc[512];
    const int t = threadIdx.x;
    const int isS = blockIdx.x;                 // 0: dst split, 1: src split
    const int* hsrc = hist2 + (isS ? nb : 0);
    int* base = isS ? sbase : dbase;
    int* cur  = isS ? scursor : dcursor;
    int v = (t < nb) ? hsrc[t] : 0;
    sc[t] = v;
    __syncthreads();
    #pragma unroll
    for (int d = 1; d < 512; d <<= 1) {
        int tv = (t >= d) ? sc[t - d] : 0;
        __syncthreads();
        sc[t] += tv;
        __syncthreads();
    }
    const int excl = sc[t] - v;                 // exclusive prefix
    if (t < nb) { base[t] = excl; cur[t] = excl; }
    if (t == nb) {
        base[t] = excl;                         // total
        if (!isS) row_start[n_nodes] = excl;
    }
}

// K2b: serial fallback (only if nb >= 512; never for this problem size).
__global__ void scan_serial_kernel(const int* __restrict__ hist2,
                                   int* __restrict__ dbase, int* __restrict__ dcursor,
                                   int* __restrict__ sbase, int* __restrict__ scursor,
                                   int* __restrict__ row_start,
                                   int nb, int n_nodes) {
    if (threadIdx.x == 0 && blockIdx.x == 0) {
        int acc = 0;
        for (int i = 0; i < nb; ++i) { dbase[i] = acc; dcursor[i] = acc; acc += hist2[i]; }
        dbase[nb] = acc;
        row_start[n_nodes] = acc;
        acc = 0;
        for (int i = 0; i < nb; ++i) { sbase[i] = acc; scursor[i] = acc; acc += hist2[nb + i]; }
        sbase[nb] = acc;
    }
}

// ---------------------------------------------------------------------------
// K3: dual multisplit, one edge pass. (a) packed (src<<8 | dst&255) into
// dst-bucket segments; (b) byte (src&255) into src-bucket segments. Segment
// reservation = one global atomic per (block,bucket) per split.
// ---------------------------------------------------------------------------
__global__ void __launch_bounds__(SC_THREADS) scatter_pairs_kernel(
        const int* __restrict__ src, const int* __restrict__ dst,
        int* __restrict__ dcursor, int* __restrict__ scursor,
        unsigned* __restrict__ pairs, unsigned char* __restrict__ sbytes,
        int n_edges, int nb) {
    __shared__ int lhd[512];    // dst-bucket count, then local cursor
    __shared__ int lbd[512];    // dst-bucket reserved global base
    __shared__ int lhs[512];    // src-bucket count, then local cursor
    __shared__ int lbs[512];    // src-bucket reserved global base
    const int t = threadIdx.x;
    for (int i = t; i < nb; i += SC_THREADS) { lhd[i] = 0; lhs[i] = 0; }
    __syncthreads();

    const int base = blockIdx.x * SC_EDGES;
    int s[SC_EPB], d[SC_EPB];
    #pragma unroll
    for (int i = 0; i < SC_EPB; ++i) {
        int e = base + i * SC_THREADS + t;
        if (e < n_edges) {
            s[i] = src[e];
            d[i] = dst[e];
            atomicAdd(&lhd[d[i] >> 8], 1);
            atomicAdd(&lhs[s[i] >> 8], 1);
        } else {
            s[i] = -1; d[i] = 0;
        }
    }
    __syncthreads();
    for (int i = t; i < nb; i += SC_THREADS) {
        int c = lhd[i];
        lbd[i] = c ? atomicAdd(&dcursor[i], c) : 0;
        lhd[i] = 0;
        c = lhs[i];
        lbs[i] = c ? atomicAdd(&scursor[i], c) : 0;
        lhs[i] = 0;
    }
    __syncthreads();
    #pragma unroll
    for (int i = 0; i < SC_EPB; ++i) {
        if (s[i] >= 0) {
            int bkt = d[i] >> 8;
            int pos = lbd[bkt] + atomicAdd(&lhd[bkt], 1);
            pairs[pos] = ((unsigned)s[i] << 8) | (unsigned)(d[i] & 255);
            int sb = s[i] >> 8;
            int spos = lbs[sb] + atomicAdd(&lhs[sb], 1);
            sbytes[spos] = (unsigned char)(s[i] & 255);
        }
    }
}

// ---------------------------------------------------------------------------
// K4: bucket -> exact CSR. One block per dst-bucket: LDS histogram of
// dst&255, block scan -> row_start, scatter src into csr_src (writes land in
// a ~32 KB window -> L2 absorbs).
// ---------------------------------------------------------------------------
__global__ void __launch_bounds__(256) bucket2csr_kernel(
        const unsigned* __restrict__ pairs, const int* __restrict__ bucket_base,
        int* __restrict__ row_start, int* __restrict__ csr_src, int n_nodes) {
    __shared__ int cnt[BROWS];
    __shared__ int scan[BROWS];
    const int b = blockIdx.x;
    const int beg = bucket_base[b];
    const int end = bucket_base[b + 1];
    const int rowBase = b * BROWS;

    cnt[threadIdx.x] = 0;
    __syncthreads();
    for (int i = beg + threadIdx.x; i < end; i += 256)
        atomicAdd(&cnt[pairs[i] & 255u], 1);
    __syncthreads();

    int v = cnt[threadIdx.x];
    scan[threadIdx.x] = v;
    __syncthreads();
    #pragma unroll
    for (int dstep = 1; dstep < 256; dstep <<= 1) {
        int tv = (threadIdx.x >= dstep) ? scan[threadIdx.x - dstep] : 0;
        __syncthreads();
        scan[threadIdx.x] += tv;
        __syncthreads();
    }
    const int excl = scan[threadIdx.x] - v;

    const int row = rowBase + threadIdx.x;
    if (row < n_nodes) row_start[row] = beg + excl;
    cnt[threadIdx.x] = beg + excl;  // reuse as cursor
    __syncthreads();

    for (int i = beg + threadIdx.x; i < end; i += 256) {
        unsigned p = pairs[i];
        int pos = atomicAdd(&cnt[p & 255u], 1);
        csr_src[pos] = (int)(p >> 8);
    }
}

// ---------------------------------------------------------------------------
// K5: out_deg from src-bucket bytes. One block per src-bucket; LDS count of
// the 256 node slots, coalesced out_deg write. No global atomics.
// ---------------------------------------------------------------------------
__global__ void __launch_bounds__(256) count_src_kernel(
        const unsigned char* __restrict__ sbytes, const int* __restrict__ sbase,
        int* __restrict__ out_deg, int n_nodes) {
    __shared__ int cnt[BROWS];
    cnt[threadIdx.x] = 0;
    __syncthreads();
    const int beg = sbase[blockIdx.x];
    const int end = sbase[blockIdx.x + 1];
    for (int i = beg + threadIdx.x; i < end; i += 256)
        atomicAdd(&cnt[sbytes[i]], 1);
    __syncthreads();
    const int row = blockIdx.x * BROWS + threadIdx.x;
    if (row < n_nodes) out_deg[row] = cnt[threadIdx.x];
}

// ---------------------------------------------------------------------------
// K6: register-tiled GEMM. m[row] = (h[row] @ W) * rsqrt(max(out_deg,1)),
// stored as FP16 (halves the random-gather bytes in K7).
// ---------------------------------------------------------------------------
__global__ void __launch_bounds__(256) gemm_kernel(
        const float* __restrict__ h, const float* __restrict__ W,
        const int* __restrict__ out_deg, __half* __restrict__ m, int n_nodes) {
    __shared__ float hs[BM * HS_LD];       // 16.9 KB
    __shared__ float Ws[KC * OUT_DIM];     // 8 KB

    const int t = threadIdx.x;
    const int c = t & 15;   // col group (4 cols)
    const int g = t >> 4;   // row group (8 rows)
    const int rowBase = blockIdx.x * BM;

    float acc[8][4];
    #pragma unroll
    for (int i = 0; i < 8; ++i)
        #pragma unroll
        for (int j = 0; j < 4; ++j) acc[i][j] = 0.f;

    for (int kc = 0; kc < IN_DIM / KC; ++kc) {
        __syncthreads();
        #pragma unroll
        for (int i = 0; i < 4; ++i) {
            int idx = t + 256 * i;
            int row = idx >> 3;
            int seg = idx & 7;
            int grow = rowBase + row;
            float4 v = make_float4(0.f, 0.f, 0.f, 0.f);
            if (grow < n_nodes)
                v = *(const float4*)(h + (size_t)grow * IN_DIM + kc * KC + seg * 4);
            float* dp = &hs[row * HS_LD + seg * 4];
            dp[0] = v.x; dp[1] = v.y; dp[2] = v.z; dp[3] = v.w;
        }
        {
            const float4* Wg = (const float4*)(W + kc * KC * OUT_DIM);
            float4* Wl = (float4*)Ws;
            Wl[t] = Wg[t];
            Wl[t + 256] = Wg[t + 256];
        }
        __syncthreads();

        #pragma unroll 4
        for (int kk = 0; kk < KC; ++kk) {
            float4 bv = *(const float4*)&Ws[kk * OUT_DIM + c * 4];
            #pragma unroll
            for (int i = 0; i < 8; ++i) {
                float a = hs[(g * 8 + i) * HS_LD + kk];
                acc[i][0] += a * bv.x;
                acc[i][1] += a * bv.y;
                acc[i][2] += a * bv.z;
                acc[i][3] += a * bv.w;
            }
        }
    }

    #pragma unroll
    for (int i = 0; i < 8; ++i) {
        int row = rowBase + g * 8 + i;
        if (row < n_nodes) {
            float nr = rsqrtf(fmaxf((float)out_deg[row], 1.0f));
            union { __half2 h2[2]; uint2 u; } pk;
            pk.h2[0] = __floats2half2_rn(acc[i][0] * nr, acc[i][1] * nr);
            pk.h2[1] = __floats2half2_rn(acc[i][2] * nr, acc[i][3] * nr);
            *(uint2*)(m + (size_t)row * OUT_DIM + c * 4) = pk.u;
        }
    }
}

// ---------------------------------------------------------------------------
// K7: CSR gather, pair-processed. Gather is VALU-issue-bound (round-1: 50%
// VALUBusy = 52 us of pure VALU at ~5 ops/edge). Now: 32 lanes per edge with
// half2 (4 B) loads; each wave processes 2 edges at once (half-waves), with
// 32-bit index math. Cross-half shfl_xor(32) combine, half-width softmax
// reductions, float2 store from half 0. FP32 accumulation throughout.
// ---------------------------------------------------------------------------
__global__ void __launch_bounds__(256) gather_kernel(
        const int* __restrict__ row_start, const int* __restrict__ csr_src,
        const __half* __restrict__ m, const float* __restrict__ b,
        float* __restrict__ out, int n_nodes) {
    const int wave = threadIdx.x >> 6;
    const int lane = threadIdx.x & 63;
    const int half = lane >> 5;    // which edge of the pair
    const int c    = lane & 31;    // column pair: cols 2c, 2c+1
    const int row = blockIdx.x * 4 + wave;
    if (row >= n_nodes) return;

    const int beg = row_start[row];
    const int end = row_start[row + 1];
    const __half2* __restrict__ m2 = (const __half2*)m;   // row stride 32

    float ax = 0.f, ay = 0.f;
    int i = beg;
    // 8 pairs (16 edges) per iteration: 8 outstanding 4 B gathers per lane
    for (; i + 16 <= end; i += 16) {
        int s[8];
        #pragma unroll
        for (int k = 0; k < 8; ++k) s[k] = csr_src[i + 2 * k + half];
        #pragma unroll
        for (int k = 0; k < 8; ++k) {
            float2 f = __half22float2(m2[(unsigned)(s[k] * (OUT_DIM / 2) + c)]);
            ax += f.x; ay += f.y;
        }
    }
    for (int e = i + half; e < end; e += 2) {
        float2 f = __half22float2(m2[(unsigned)(csr_src[e] * (OUT_DIM / 2) + c)]);
        ax += f.x; ay += f.y;
    }
    // combine the two half-wave partials (lane <-> lane^32); both halves
    // then hold the full per-column sums
    ax += __shfl_xor(ax, 32, 64);
    ay += __shfl_xor(ay, 32, 64);

    float nd = rsqrtf(fmaxf((float)(end - beg), 1.0f));
    float2 bb = *(const float2*)(b + 2 * c);
    float x0 = ax * nd + bb.x;
    float x1 = ay * nd + bb.y;

    // softmax over 64 classes held as 2 per lane across each 32-lane half
    float mx = fmaxf(x0, x1);
    #pragma unroll
    for (int o = 16; o > 0; o >>= 1) mx = fmaxf(mx, __shfl_xor(mx, o, 64));
    float ex0 = expf(x0 - mx), ex1 = expf(x1 - mx);
    float s = ex0 + ex1;
    #pragma unroll
    for (int o = 16; o > 0; o >>= 1) s += __shfl_xor(s, o, 64);
    float ls = logf(s);

    if (half == 0) {
        float2 o2 = make_float2(x0 - mx - ls, x1 - mx - ls);
        *(float2*)(out + (size_t)row * OUT_DIM + 2 * c) = o2;
    }
}

// ---------------------------------------------------------------------------
static inline size_t align16(size_t x) { return (x + 15) & ~(size_t)15; }

extern "C" void kernel_launch(void* const* d_in, const int* in_sizes, int n_in,
                              void* d_out, int out_size, void* d_ws, size_t ws_size,
                              hipStream_t stream) {
    const float* h = (const float*)d_in[0];
    const float* W = (const float*)d_in[1];
    const float* b = (const float*)d_in[2];
    const int* edges = (const int*)d_in[3];

    const int out_dim = in_sizes[2];            // 64
    const int in_dim  = in_sizes[1] / out_dim;  // 256
    const int n_nodes = in_sizes[0] / in_dim;   // 100000
    const int n_edges = in_sizes[3] / 2;        // 3200000

    const int* src = edges;
    const int* dst = edges + n_edges;

    float* out = (float*)d_out;

    const int nb = (n_nodes + BROWS - 1) / BROWS;  // 391 buckets

    // workspace carve-up
    char* ws = (char*)d_ws;
    size_t off = 0;
    int* out_deg     = (int*)(ws + off); off = align16(off + (size_t)n_nodes * 4);
    int* row_start   = (int*)(ws + off); off = align16(off + (size_t)(n_nodes + 1) * 4);
    int* hist2       = (int*)(ws + off); off = align16(off + (size_t)(2 * nb) * 4);
    int* dbase       = (int*)(ws + off); off = align16(off + (size_t)(nb + 1) * 4);
    int* dcursor     = (int*)(ws + off); off = align16(off + (size_t)nb * 4);
    int* sbase       = (int*)(ws + off); off = align16(off + (size_t)(nb + 1) * 4);
    int* scursor     = (int*)(ws + off); off = align16(off + (size_t)nb * 4);
    __half* m        = (__half*)(ws + off); off = align16(off + (size_t)n_nodes * OUT_DIM * 2);
    unsigned* pairs  = (unsigned*)(ws + off); off = align16(off + (size_t)n_edges * 4);
    int* csr_src     = (int*)(ws + off); off = align16(off + (size_t)n_edges * 4);
    // sbytes aliases m's storage: written by scatter, consumed by count_src,
    // both strictly before gemm writes m (serial stream ordering).
    // n_edges bytes (3.2 MB) <= n_nodes*OUT_DIM*2 bytes (12.8 MB).
    unsigned char* sbytes = (unsigned char*)m;

    (void)hipMemsetAsync(hist2, 0, (size_t)(2 * nb) * sizeof(int), stream);

    const int hist_blocks = (n_edges + HIST_EDGES - 1) / HIST_EDGES;
    const int sc_blocks   = (n_edges + SC_EDGES - 1) / SC_EDGES;

    hist_kernel<<<hist_blocks, 256, 0, stream>>>(src, dst, hist2, n_edges, nb);
    if (nb + 1 <= 512) {
        scan2_kernel<<<2, 512, 0, stream>>>(hist2, dbase, dcursor, sbase, scursor,
                                            row_start, nb, n_nodes);
    } else {
        scan_serial_kernel<<<1, 64, 0, stream>>>(hist2, dbase, dcursor, sbase, scursor,
                                                 row_start, nb, n_nodes);
    }
    scatter_pairs_kernel<<<sc_blocks, SC_THREADS, 0, stream>>>(
        src, dst, dcursor, scursor, pairs, sbytes, n_edges, nb);
    bucket2csr_kernel<<<nb, 256, 0, stream>>>(pairs, dbase, row_start, csr_src, n_nodes);
    count_src_kernel<<<nb, 256, 0, stream>>>(sbytes, sbase, out_deg, n_nodes);

    gemm_kernel<<<(n_nodes + BM - 1) / BM, 256, 0, stream>>>(h, W, out_deg, m, n_nodes);

    gather_kernel<<<(n_nodes + 3) / 4, 256, 0, stream>>>(row_start, csr_src, m, b, out, n_nodes);
}

// Round 4
// 405.262 us; speedup vs baseline: 4.3512x; 1.0510x over previous
//
#include <hip/hip_runtime.h>
#include <hip/hip_fp16.h>
#include <math.h>

#define IN_DIM 256
#define OUT_DIM 64
#define BROWS 256             // nodes per bucket
#define HIST_EDGES 8192       // edges per hist block
#define SC_THREADS 512
#define SC_EPB 16
#define SC_EDGES (SC_THREADS * SC_EPB)  // 8192 edges per scatter block
#define BM 128                // gemm rows per block
#define KC 32                 // gemm k-chunk
#define HS_LD 33              // padded leading dim of h tile in LDS
#define CSR_CAP 12288         // LDS CSR capacity per bucket (mean 8184, sigma ~90)

// ---------------------------------------------------------------------------
// K1: dual bucket histogram (dst>>8 and src>>8), LDS-privatized, int4 edge
// loads (4 edges per VMEM instr), NO per-node atomics.
// hist layout: [0..nb) dst buckets, [nb..2nb) src buckets.
// ---------------------------------------------------------------------------
__global__ void __launch_bounds__(256) hist_kernel(
        const int* __restrict__ src, const int* __restrict__ dst,
        int* __restrict__ hist2, int n_edges, int nb) {
    __shared__ int lhd[512];
    __shared__ int lhs[512];
    for (int i = threadIdx.x; i < nb; i += 256) { lhd[i] = 0; lhs[i] = 0; }
    __syncthreads();
    const int base = blockIdx.x * HIST_EDGES;
    if (base + HIST_EDGES <= n_edges) {
        const int4* s4 = (const int4*)(src + base);
        const int4* d4 = (const int4*)(dst + base);
        for (int i = threadIdx.x; i < HIST_EDGES / 4; i += 256) {
            int4 a = s4[i];
            int4 c = d4[i];
            atomicAdd(&lhs[a.x >> 8], 1); atomicAdd(&lhs[a.y >> 8], 1);
            atomicAdd(&lhs[a.z >> 8], 1); atomicAdd(&lhs[a.w >> 8], 1);
            atomicAdd(&lhd[c.x >> 8], 1); atomicAdd(&lhd[c.y >> 8], 1);
            atomicAdd(&lhd[c.z >> 8], 1); atomicAdd(&lhd[c.w >> 8], 1);
        }
    } else {
        for (int i = threadIdx.x; i < HIST_EDGES; i += 256) {
            int e = base + i;
            if (e < n_edges) {
                atomicAdd(&lhd[dst[e] >> 8], 1);
                atomicAdd(&lhs[src[e] >> 8], 1);
            }
        }
    }
    __syncthreads();
    for (int i = threadIdx.x; i < nb; i += 256) {
        if (lhd[i]) atomicAdd(&hist2[i], lhd[i]);
        if (lhs[i]) atomicAdd(&hist2[nb + i], lhs[i]);
    }
}

// ---------------------------------------------------------------------------
// K2a: parallel exclusive scans of both bucket histograms. Block 0 scans the
// dst histogram, block 1 the src histogram (Hillis-Steele; needs nb < 512).
// ---------------------------------------------------------------------------
__global__ void __launch_bounds__(512) scan2_kernel(
        const int* __restrict__ hist2,
        int* __restrict__ dbase, int* __restrict__ dcursor,
        int* __restrict__ sbase, int* __restrict__ scursor, int nb) {
    __shared__ int sc[512];
    const int t = threadIdx.x;
    const int isS = blockIdx.x;                 // 0: dst split, 1: src split
    const int* hsrc = hist2 + (isS ? nb : 0);
    int* base = isS ? sbase : dbase;
    int* cur  = isS ? scursor : dcursor;
    int v = (t < nb) ? hsrc[t] : 0;
    sc[t] = v;
    __syncthreads();
    #pragma unroll
    for (int d = 1; d < 512; d <<= 1) {
        int tv = (t >= d) ? sc[t - d] : 0;
        __syncthreads();
        sc[t] += tv;
        __syncthreads();
    }
    const int excl = sc[t] - v;                 // exclusive prefix
    if (t < nb) { base[t] = excl; cur[t] = excl; }
    if (t == nb) base[t] = excl;                // total
}

// K2b: serial fallback (only if nb >= 512; never for this problem size).
__global__ void scan_serial_kernel(const int* __restrict__ hist2,
                                   int* __restrict__ dbase, int* __restrict__ dcursor,
                                   int* __restrict__ sbase, int* __restrict__ scursor,
                                   int nb) {
    if (threadIdx.x == 0 && blockIdx.x == 0) {
        int acc = 0;
        for (int i = 0; i < nb; ++i) { dbase[i] = acc; dcursor[i] = acc; acc += hist2[i]; }
        dbase[nb] = acc;
        acc = 0;
        for (int i = 0; i < nb; ++i) { sbase[i] = acc; scursor[i] = acc; acc += hist2[nb + i]; }
        sbase[nb] = acc;
    }
}

// ---------------------------------------------------------------------------
// K3: dual multisplit, one edge pass, int4 edge loads. (a) packed
// (src<<8 | dst&255) into dst-bucket segments; (b) byte (src&255) into
// src-bucket segments. Reservation = one global atomic per (block,bucket).
// ---------------------------------------------------------------------------
__global__ void __launch_bounds__(SC_THREADS) scatter_pairs_kernel(
        const int* __restrict__ src, const int* __restrict__ dst,
        int* __restrict__ dcursor, int* __restrict__ scursor,
        unsigned* __restrict__ pairs, unsigned char* __restrict__ sbytes,
        int n_edges, int nb) {
    __shared__ int lhd[512];    // dst-bucket count, then local cursor
    __shared__ int lbd[512];    // dst-bucket reserved global base
    __shared__ int lhs[512];    // src-bucket count, then local cursor
    __shared__ int lbs[512];    // src-bucket reserved global base
    const int t = threadIdx.x;
    for (int i = t; i < nb; i += SC_THREADS) { lhd[i] = 0; lhs[i] = 0; }
    __syncthreads();

    const int base = blockIdx.x * SC_EDGES;
    int s[SC_EPB], d[SC_EPB];
    if (base + SC_EDGES <= n_edges) {
        const int4* s4 = (const int4*)(src + base);
        const int4* d4 = (const int4*)(dst + base);
        #pragma unroll
        for (int j = 0; j < SC_EPB / 4; ++j) {
            int4 a = s4[j * SC_THREADS + t];
            int4 c = d4[j * SC_THREADS + t];
            s[4*j+0] = a.x; s[4*j+1] = a.y; s[4*j+2] = a.z; s[4*j+3] = a.w;
            d[4*j+0] = c.x; d[4*j+1] = c.y; d[4*j+2] = c.z; d[4*j+3] = c.w;
        }
        #pragma unroll
        for (int i = 0; i < SC_EPB; ++i) {
            atomicAdd(&lhd[d[i] >> 8], 1);
            atomicAdd(&lhs[s[i] >> 8], 1);
        }
    } else {
        #pragma unroll
        for (int i = 0; i < SC_EPB; ++i) {
            int e = base + i * SC_THREADS + t;
            if (e < n_edges) {
                s[i] = src[e];
                d[i] = dst[e];
                atomicAdd(&lhd[d[i] >> 8], 1);
                atomicAdd(&lhs[s[i] >> 8], 1);
            } else {
                s[i] = -1; d[i] = 0;
            }
        }
    }
    __syncthreads();
    for (int i = t; i < nb; i += SC_THREADS) {
        int c = lhd[i];
        lbd[i] = c ? atomicAdd(&dcursor[i], c) : 0;
        lhd[i] = 0;
        c = lhs[i];
        lbs[i] = c ? atomicAdd(&scursor[i], c) : 0;
        lhs[i] = 0;
    }
    __syncthreads();
    #pragma unroll
    for (int i = 0; i < SC_EPB; ++i) {
        if (s[i] >= 0) {
            int bkt = d[i] >> 8;
            int pos = lbd[bkt] + atomicAdd(&lhd[bkt], 1);
            pairs[pos] = ((unsigned)s[i] << 8) | (unsigned)(d[i] & 255);
            int sb = s[i] >> 8;
            int spos = lbs[sb] + atomicAdd(&lhs[sb], 1);
            sbytes[spos] = (unsigned char)(s[i] & 255);
        }
    }
}

// ---------------------------------------------------------------------------
// K4: out_deg from src-bucket bytes. One block per src-bucket; LDS count of
// the 256 node slots, coalesced out_deg write. No global atomics.
// ---------------------------------------------------------------------------
__global__ void __launch_bounds__(256) count_src_kernel(
        const unsigned char* __restrict__ sbytes, const int* __restrict__ sbase,
        int* __restrict__ out_deg, int n_nodes) {
    __shared__ int cnt[BROWS];
    cnt[threadIdx.x] = 0;
    __syncthreads();
    const int beg = sbase[blockIdx.x];
    const int end = sbase[blockIdx.x + 1];
    for (int i = beg + threadIdx.x; i < end; i += 256)
        atomicAdd(&cnt[sbytes[i]], 1);
    __syncthreads();
    const int row = blockIdx.x * BROWS + threadIdx.x;
    if (row < n_nodes) out_deg[row] = cnt[threadIdx.x];
}

// ---------------------------------------------------------------------------
// K5: register-tiled GEMM. m[row] = (h[row] @ W) * rsqrt(max(out_deg,1)),
// stored as FP16 (halves the random-gather bytes in K6).
// ---------------------------------------------------------------------------
__global__ void __launch_bounds__(256) gemm_kernel(
        const float* __restrict__ h, const float* __restrict__ W,
        const int* __restrict__ out_deg, __half* __restrict__ m, int n_nodes) {
    __shared__ float hs[BM * HS_LD];       // 16.9 KB
    __shared__ float Ws[KC * OUT_DIM];     // 8 KB

    const int t = threadIdx.x;
    const int c = t & 15;   // col group (4 cols)
    const int g = t >> 4;   // row group (8 rows)
    const int rowBase = blockIdx.x * BM;

    float acc[8][4];
    #pragma unroll
    for (int i = 0; i < 8; ++i)
        #pragma unroll
        for (int j = 0; j < 4; ++j) acc[i][j] = 0.f;

    for (int kc = 0; kc < IN_DIM / KC; ++kc) {
        __syncthreads();
        #pragma unroll
        for (int i = 0; i < 4; ++i) {
            int idx = t + 256 * i;
            int row = idx >> 3;
            int seg = idx & 7;
            int grow = rowBase + row;
            float4 v = make_float4(0.f, 0.f, 0.f, 0.f);
            if (grow < n_nodes)
                v = *(const float4*)(h + (size_t)grow * IN_DIM + kc * KC + seg * 4);
            float* dp = &hs[row * HS_LD + seg * 4];
            dp[0] = v.x; dp[1] = v.y; dp[2] = v.z; dp[3] = v.w;
        }
        {
            const float4* Wg = (const float4*)(W + kc * KC * OUT_DIM);
            float4* Wl = (float4*)Ws;
            Wl[t] = Wg[t];
            Wl[t + 256] = Wg[t + 256];
        }
        __syncthreads();

        #pragma unroll 4
        for (int kk = 0; kk < KC; ++kk) {
            float4 bv = *(const float4*)&Ws[kk * OUT_DIM + c * 4];
            #pragma unroll
            for (int i = 0; i < 8; ++i) {
                float a = hs[(g * 8 + i) * HS_LD + kk];
                acc[i][0] += a * bv.x;
                acc[i][1] += a * bv.y;
                acc[i][2] += a * bv.z;
                acc[i][3] += a * bv.w;
            }
        }
    }

    #pragma unroll
    for (int i = 0; i < 8; ++i) {
        int row = rowBase + g * 8 + i;
        if (row < n_nodes) {
            float nr = rsqrtf(fmaxf((float)out_deg[row], 1.0f));
            union { __half2 h2[2]; uint2 u; } pk;
            pk.h2[0] = __floats2half2_rn(acc[i][0] * nr, acc[i][1] * nr);
            pk.h2[1] = __floats2half2_rn(acc[i][2] * nr, acc[i][3] * nr);
            *(uint2*)(m + (size_t)row * OUT_DIM + c * 4) = pk.u;
        }
    }
}

// ---------------------------------------------------------------------------
// K6: fused bucket2csr + gather. One block per dst-bucket (512 thr, ~52 KB
// LDS). Phase 1-3: exact in-LDS CSR of the bucket (int LDS atomics: count,
// scan, position-scatter of the 24-bit src ids). Phase 4: round-3's
// pair-processed gather (2 edges per wave via half-waves, half2 loads of
// fp16 m rows), indices read from LDS (broadcast), fused norm_dst + bias +
// log_softmax. Eliminates csr_src (25.6 MB traffic), row_start, and the
// 12.8 MB global index loads. 391 uniform blocks at 3 blocks/CU -> all
// co-resident, no tail.
// ---------------------------------------------------------------------------
__global__ void __launch_bounds__(512) bucket_gather_kernel(
        const unsigned* __restrict__ pairs, const int* __restrict__ dbase,
        const __half* __restrict__ m, const float* __restrict__ b,
        float* __restrict__ out, int n_nodes) {
    __shared__ int cnt[BROWS];      // per-row edge count
    __shared__ int rofs[BROWS];     // inclusive scan of cnt
    __shared__ int cur[BROWS];      // scatter cursor
    __shared__ int csr[CSR_CAP];    // row-sorted src ids (48 KB)

    const int t = threadIdx.x;
    const int bkt = blockIdx.x;
    const int beg = dbase[bkt];
    const int end = dbase[bkt + 1];
    const int seg = end - beg;
    const int rowBase = bkt * BROWS;

    const int wave = t >> 6;
    const int lane = t & 63;
    const int half = lane >> 5;     // which edge of the pair
    const int c    = lane & 31;     // column pair: cols 2c, 2c+1
    const __half2* __restrict__ m2 = (const __half2*)m;   // row stride 32
    const float2 bb = *(const float2*)(b + 2 * c);

    if (t < BROWS) cnt[t] = 0;
    __syncthreads();

    if (seg <= CSR_CAP) {
        // ---- phase 1: per-row count
        for (int i = beg + t; i < end; i += 512)
            atomicAdd(&cnt[pairs[i] & 255u], 1);
        __syncthreads();
        // ---- phase 2: inclusive scan (Hillis-Steele over 256)
        if (t < BROWS) rofs[t] = cnt[t];
        __syncthreads();
        #pragma unroll
        for (int d = 1; d < BROWS; d <<= 1) {
            int tv = (t < BROWS && t >= d) ? rofs[t - d] : 0;
            __syncthreads();
            if (t < BROWS) rofs[t] += tv;
            __syncthreads();
        }
        if (t < BROWS) cur[t] = rofs[t] - cnt[t];
        __syncthreads();
        // ---- phase 3: position-scatter src ids into LDS CSR (L2-hot re-read)
        for (int i = beg + t; i < end; i += 512) {
            unsigned p = pairs[i];
            int pos = atomicAdd(&cur[p & 255u], 1);
            csr[pos] = (int)(p >> 8);
        }
        __syncthreads();
        // ---- phase 4: per-row gather + softmax (32 rows per wave)
        for (int r = wave; r < BROWS; r += 8) {
            const int row = rowBase + r;
            if (row >= n_nodes) continue;          // uniform per wave
            const int cend = rofs[r];
            const int cbeg = cend - cnt[r];
            float ax = 0.f, ay = 0.f;
            int i = cbeg;
            for (; i + 16 <= cend; i += 16) {
                int s[8];
                #pragma unroll
                for (int k = 0; k < 8; ++k) s[k] = csr[i + 2 * k + half];
                #pragma unroll
                for (int k = 0; k < 8; ++k) {
                    float2 f = __half22float2(m2[(unsigned)(s[k] * (OUT_DIM / 2) + c)]);
                    ax += f.x; ay += f.y;
                }
            }
            for (int e = i + half; e < cend; e += 2) {
                float2 f = __half22float2(m2[(unsigned)(csr[e] * (OUT_DIM / 2) + c)]);
                ax += f.x; ay += f.y;
            }
            ax += __shfl_xor(ax, 32, 64);
            ay += __shfl_xor(ay, 32, 64);

            float nd = rsqrtf(fmaxf((float)cnt[r], 1.0f));
            float x0 = ax * nd + bb.x;
            float x1 = ay * nd + bb.y;
            float mx = fmaxf(x0, x1);
            #pragma unroll
            for (int o = 16; o > 0; o >>= 1) mx = fmaxf(mx, __shfl_xor(mx, o, 64));
            float ex0 = expf(x0 - mx), ex1 = expf(x1 - mx);
            float sm = ex0 + ex1;
            #pragma unroll
            for (int o = 16; o > 0; o >>= 1) sm += __shfl_xor(sm, o, 64);
            float ls = logf(sm);
            if (half == 0)
                *(float2*)(out + (size_t)row * OUT_DIM + 2 * c) =
                    make_float2(x0 - mx - ls, x1 - mx - ls);
        }
    } else {
        // ---- slow fallback (pathological bucket > CSR_CAP; never on this
        // input): every lane scans the whole segment for its rows.
        for (int r = wave; r < BROWS; r += 8) {
            const int row = rowBase + r;
            if (row >= n_nodes) continue;
            float ax = 0.f, ay = 0.f;
            int deg = 0;
            for (int e = beg; e < end; ++e) {
                unsigned p = pairs[e];
                if ((int)(p & 255u) == r) {
                    ++deg;
                    float2 f = __half22float2(m2[(unsigned)((p >> 8) * (OUT_DIM / 2) + c)]);
                    ax += f.x; ay += f.y;
                }
            }
            // both halves hold full sums: no cross-half combine
            float nd = rsqrtf(fmaxf((float)deg, 1.0f));
            float x0 = ax * nd + bb.x;
            float x1 = ay * nd + bb.y;
            float mx = fmaxf(x0, x1);
            #pragma unroll
            for (int o = 16; o > 0; o >>= 1) mx = fmaxf(mx, __shfl_xor(mx, o, 64));
            float ex0 = expf(x0 - mx), ex1 = expf(x1 - mx);
            float sm = ex0 + ex1;
            #pragma unroll
            for (int o = 16; o > 0; o >>= 1) sm += __shfl_xor(sm, o, 64);
            float ls = logf(sm);
            if (half == 0)
                *(float2*)(out + (size_t)row * OUT_DIM + 2 * c) =
                    make_float2(x0 - mx - ls, x1 - mx - ls);
        }
    }
}

// ---------------------------------------------------------------------------
static inline size_t align16(size_t x) { return (x + 15) & ~(size_t)15; }

extern "C" void kernel_launch(void* const* d_in, const int* in_sizes, int n_in,
                              void* d_out, int out_size, void* d_ws, size_t ws_size,
                              hipStream_t stream) {
    const float* h = (const float*)d_in[0];
    const float* W = (const float*)d_in[1];
    const float* b = (const float*)d_in[2];
    const int* edges = (const int*)d_in[3];

    const int out_dim = in_sizes[2];            // 64
    const int in_dim  = in_sizes[1] / out_dim;  // 256
    const int n_nodes = in_sizes[0] / in_dim;   // 100000
    const int n_edges = in_sizes[3] / 2;        // 3200000

    const int* src = edges;
    const int* dst = edges + n_edges;

    float* out = (float*)d_out;

    const int nb = (n_nodes + BROWS - 1) / BROWS;  // 391 buckets

    // workspace carve-up
    char* ws = (char*)d_ws;
    size_t off = 0;
    int* out_deg     = (int*)(ws + off); off = align16(off + (size_t)n_nodes * 4);
    int* hist2       = (int*)(ws + off); off = align16(off + (size_t)(2 * nb) * 4);
    int* dbase       = (int*)(ws + off); off = align16(off + (size_t)(nb + 1) * 4);
    int* dcursor     = (int*)(ws + off); off = align16(off + (size_t)nb * 4);
    int* sbase       = (int*)(ws + off); off = align16(off + (size_t)(nb + 1) * 4);
    int* scursor     = (int*)(ws + off); off = align16(off + (size_t)nb * 4);
    __half* m        = (__half*)(ws + off); off = align16(off + (size_t)n_nodes * OUT_DIM * 2);
    unsigned* pairs  = (unsigned*)(ws + off); off = align16(off + (size_t)n_edges * 4);
    // sbytes aliases m's storage: written by scatter, consumed by count_src,
    // both strictly before gemm writes m (serial stream ordering).
    // n_edges bytes (3.2 MB) <= n_nodes*OUT_DIM*2 bytes (12.8 MB).
    unsigned char* sbytes = (unsigned char*)m;

    (void)hipMemsetAsync(hist2, 0, (size_t)(2 * nb) * sizeof(int), stream);

    const int hist_blocks = (n_edges + HIST_EDGES - 1) / HIST_EDGES;
    const int sc_blocks   = (n_edges + SC_EDGES - 1) / SC_EDGES;

    hist_kernel<<<hist_blocks, 256, 0, stream>>>(src, dst, hist2, n_edges, nb);
    if (nb + 1 <= 512) {
        scan2_kernel<<<2, 512, 0, stream>>>(hist2, dbase, dcursor, sbase, scursor, nb);
    } else {
        scan_serial_kernel<<<1, 64, 0, stream>>>(hist2, dbase, dcursor, sbase, scursor, nb);
    }
    scatter_pairs_kernel<<<sc_blocks, SC_THREADS, 0, stream>>>(
        src, dst, dcursor, scursor, pairs, sbytes, n_edges, nb);
    count_src_kernel<<<nb, 256, 0, stream>>>(sbytes, sbase, out_deg, n_nodes);

    gemm_kernel<<<(n_nodes + BM - 1) / BM, 256, 0, stream>>>(h, W, out_deg, m, n_nodes);

    bucket_gather_kernel<<<nb, 512, 0, stream>>>(pairs, dbase, m, b, out, n_nodes);
}

// Round 5
// 390.489 us; speedup vs baseline: 4.5158x; 1.0378x over previous
//
#include <hip/hip_runtime.h>
#include <hip/hip_fp16.h>
#include <math.h>

#define IN_DIM 256
#define OUT_DIM 64
#define BROWS 256             // nodes per bucket (pairs format)
#define GROWS 128             // rows per gather block (half bucket)
#define HIST_EDGES 8192       // edges per hist block
#define SC_THREADS 512
#define SC_EPB 16
#define SC_EDGES (SC_THREADS * SC_EPB)  // 8192 edges per scatter block
#define BM 128                // gemm rows per block
#define KC 32                 // gemm k-chunk
#define HS_LD 33              // padded leading dim of h tile in LDS
#define CSR_CAP 5120          // LDS CSR capacity per half-bucket (mean 4092, sigma ~64)

// ---------------------------------------------------------------------------
// K1: dual bucket histogram (dst>>8 and src>>8), LDS-privatized, int4 edge
// loads (4 edges per VMEM instr), NO per-node atomics.
// hist layout: [0..nb) dst buckets, [nb..2nb) src buckets.
// ---------------------------------------------------------------------------
__global__ void __launch_bounds__(256) hist_kernel(
        const int* __restrict__ src, const int* __restrict__ dst,
        int* __restrict__ hist2, int n_edges, int nb) {
    __shared__ int lhd[512];
    __shared__ int lhs[512];
    for (int i = threadIdx.x; i < nb; i += 256) { lhd[i] = 0; lhs[i] = 0; }
    __syncthreads();
    const int base = blockIdx.x * HIST_EDGES;
    if (base + HIST_EDGES <= n_edges) {
        const int4* s4 = (const int4*)(src + base);
        const int4* d4 = (const int4*)(dst + base);
        for (int i = threadIdx.x; i < HIST_EDGES / 4; i += 256) {
            int4 a = s4[i];
            int4 c = d4[i];
            atomicAdd(&lhs[a.x >> 8], 1); atomicAdd(&lhs[a.y >> 8], 1);
            atomicAdd(&lhs[a.z >> 8], 1); atomicAdd(&lhs[a.w >> 8], 1);
            atomicAdd(&lhd[c.x >> 8], 1); atomicAdd(&lhd[c.y >> 8], 1);
            atomicAdd(&lhd[c.z >> 8], 1); atomicAdd(&lhd[c.w >> 8], 1);
        }
    } else {
        for (int i = threadIdx.x; i < HIST_EDGES; i += 256) {
            int e = base + i;
            if (e < n_edges) {
                atomicAdd(&lhd[dst[e] >> 8], 1);
                atomicAdd(&lhs[src[e] >> 8], 1);
            }
        }
    }
    __syncthreads();
    for (int i = threadIdx.x; i < nb; i += 256) {
        if (lhd[i]) atomicAdd(&hist2[i], lhd[i]);
        if (lhs[i]) atomicAdd(&hist2[nb + i], lhs[i]);
    }
}

// ---------------------------------------------------------------------------
// K2a: parallel exclusive scans of both bucket histograms. Block 0 scans the
// dst histogram, block 1 the src histogram (Hillis-Steele; needs nb < 512).
// ---------------------------------------------------------------------------
__global__ void __launch_bounds__(512) scan2_kernel(
        const int* __restrict__ hist2,
        int* __restrict__ dbase, int* __restrict__ dcursor,
        int* __restrict__ sbase, int* __restrict__ scursor, int nb) {
    __shared__ int sc[512];
    const int t = threadIdx.x;
    const int isS = blockIdx.x;                 // 0: dst split, 1: src split
    const int* hsrc = hist2 + (isS ? nb : 0);
    int* base = isS ? sbase : dbase;
    int* cur  = isS ? scursor : dcursor;
    int v = (t < nb) ? hsrc[t] : 0;
    sc[t] = v;
    __syncthreads();
    #pragma unroll
    for (int d = 1; d < 512; d <<= 1) {
        int tv = (t >= d) ? sc[t - d] : 0;
        __syncthreads();
        sc[t] += tv;
        __syncthreads();
    }
    const int excl = sc[t] - v;                 // exclusive prefix
    if (t < nb) { base[t] = excl; cur[t] = excl; }
    if (t == nb) base[t] = excl;                // total
}

// K2b: serial fallback (only if nb >= 512; never for this problem size).
__global__ void scan_serial_kernel(const int* __restrict__ hist2,
                                   int* __restrict__ dbase, int* __restrict__ dcursor,
                                   int* __restrict__ sbase, int* __restrict__ scursor,
                                   int nb) {
    if (threadIdx.x == 0 && blockIdx.x == 0) {
        int acc = 0;
        for (int i = 0; i < nb; ++i) { dbase[i] = acc; dcursor[i] = acc; acc += hist2[i]; }
        dbase[nb] = acc;
        acc = 0;
        for (int i = 0; i < nb; ++i) { sbase[i] = acc; scursor[i] = acc; acc += hist2[nb + i]; }
        sbase[nb] = acc;
    }
}

// ---------------------------------------------------------------------------
// K3: dual multisplit, one edge pass, int4 edge loads. (a) packed
// (src<<8 | dst&255) into dst-bucket segments; (b) byte (src&255) into
// src-bucket segments. Reservation = one global atomic per (block,bucket).
// ---------------------------------------------------------------------------
__global__ void __launch_bounds__(SC_THREADS) scatter_pairs_kernel(
        const int* __restrict__ src, const int* __restrict__ dst,
        int* __restrict__ dcursor, int* __restrict__ scursor,
        unsigned* __restrict__ pairs, unsigned char* __restrict__ sbytes,
        int n_edges, int nb) {
    __shared__ int lhd[512];    // dst-bucket count, then local cursor
    __shared__ int lbd[512];    // dst-bucket reserved global base
    __shared__ int lhs[512];    // src-bucket count, then local cursor
    __shared__ int lbs[512];    // src-bucket reserved global base
    const int t = threadIdx.x;
    for (int i = t; i < nb; i += SC_THREADS) { lhd[i] = 0; lhs[i] = 0; }
    __syncthreads();

    const int base = blockIdx.x * SC_EDGES;
    int s[SC_EPB], d[SC_EPB];
    if (base + SC_EDGES <= n_edges) {
        const int4* s4 = (const int4*)(src + base);
        const int4* d4 = (const int4*)(dst + base);
        #pragma unroll
        for (int j = 0; j < SC_EPB / 4; ++j) {
            int4 a = s4[j * SC_THREADS + t];
            int4 c = d4[j * SC_THREADS + t];
            s[4*j+0] = a.x; s[4*j+1] = a.y; s[4*j+2] = a.z; s[4*j+3] = a.w;
            d[4*j+0] = c.x; d[4*j+1] = c.y; d[4*j+2] = c.z; d[4*j+3] = c.w;
        }
        #pragma unroll
        for (int i = 0; i < SC_EPB; ++i) {
            atomicAdd(&lhd[d[i] >> 8], 1);
            atomicAdd(&lhs[s[i] >> 8], 1);
        }
    } else {
        #pragma unroll
        for (int i = 0; i < SC_EPB; ++i) {
            int e = base + i * SC_THREADS + t;
            if (e < n_edges) {
                s[i] = src[e];
                d[i] = dst[e];
                atomicAdd(&lhd[d[i] >> 8], 1);
                atomicAdd(&lhs[s[i] >> 8], 1);
            } else {
                s[i] = -1; d[i] = 0;
            }
        }
    }
    __syncthreads();
    for (int i = t; i < nb; i += SC_THREADS) {
        int c = lhd[i];
        lbd[i] = c ? atomicAdd(&dcursor[i], c) : 0;
        lhd[i] = 0;
        c = lhs[i];
        lbs[i] = c ? atomicAdd(&scursor[i], c) : 0;
        lhs[i] = 0;
    }
    __syncthreads();
    #pragma unroll
    for (int i = 0; i < SC_EPB; ++i) {
        if (s[i] >= 0) {
            int bkt = d[i] >> 8;
            int pos = lbd[bkt] + atomicAdd(&lhd[bkt], 1);
            pairs[pos] = ((unsigned)s[i] << 8) | (unsigned)(d[i] & 255);
            int sb = s[i] >> 8;
            int spos = lbs[sb] + atomicAdd(&lhs[sb], 1);
            sbytes[spos] = (unsigned char)(s[i] & 255);
        }
    }
}

// ---------------------------------------------------------------------------
// K4: out_deg from src-bucket bytes. One block per src-bucket; LDS count of
// the 256 node slots, coalesced out_deg write. No global atomics.
// ---------------------------------------------------------------------------
__global__ void __launch_bounds__(256) count_src_kernel(
        const unsigned char* __restrict__ sbytes, const int* __restrict__ sbase,
        int* __restrict__ out_deg, int n_nodes) {
    __shared__ int cnt[BROWS];
    cnt[threadIdx.x] = 0;
    __syncthreads();
    const int beg = sbase[blockIdx.x];
    const int end = sbase[blockIdx.x + 1];
    for (int i = beg + threadIdx.x; i < end; i += 256)
        atomicAdd(&cnt[sbytes[i]], 1);
    __syncthreads();
    const int row = blockIdx.x * BROWS + threadIdx.x;
    if (row < n_nodes) out_deg[row] = cnt[threadIdx.x];
}

// ---------------------------------------------------------------------------
// K5: register-tiled GEMM. m[row] = (h[row] @ W) * rsqrt(max(out_deg,1)),
// stored as FP16 (halves the random-gather bytes in K6).
// ---------------------------------------------------------------------------
__global__ void __launch_bounds__(256) gemm_kernel(
        const float* __restrict__ h, const float* __restrict__ W,
        const int* __restrict__ out_deg, __half* __restrict__ m, int n_nodes) {
    __shared__ float hs[BM * HS_LD];       // 16.9 KB
    __shared__ float Ws[KC * OUT_DIM];     // 8 KB

    const int t = threadIdx.x;
    const int c = t & 15;   // col group (4 cols)
    const int g = t >> 4;   // row group (8 rows)
    const int rowBase = blockIdx.x * BM;

    float acc[8][4];
    #pragma unroll
    for (int i = 0; i < 8; ++i)
        #pragma unroll
        for (int j = 0; j < 4; ++j) acc[i][j] = 0.f;

    for (int kc = 0; kc < IN_DIM / KC; ++kc) {
        __syncthreads();
        #pragma unroll
        for (int i = 0; i < 4; ++i) {
            int idx = t + 256 * i;
            int row = idx >> 3;
            int seg = idx & 7;
            int grow = rowBase + row;
            float4 v = make_float4(0.f, 0.f, 0.f, 0.f);
            if (grow < n_nodes)
                v = *(const float4*)(h + (size_t)grow * IN_DIM + kc * KC + seg * 4);
            float* dp = &hs[row * HS_LD + seg * 4];
            dp[0] = v.x; dp[1] = v.y; dp[2] = v.z; dp[3] = v.w;
        }
        {
            const float4* Wg = (const float4*)(W + kc * KC * OUT_DIM);
            float4* Wl = (float4*)Ws;
            Wl[t] = Wg[t];
            Wl[t + 256] = Wg[t + 256];
        }
        __syncthreads();

        #pragma unroll 4
        for (int kk = 0; kk < KC; ++kk) {
            float4 bv = *(const float4*)&Ws[kk * OUT_DIM + c * 4];
            #pragma unroll
            for (int i = 0; i < 8; ++i) {
                float a = hs[(g * 8 + i) * HS_LD + kk];
                acc[i][0] += a * bv.x;
                acc[i][1] += a * bv.y;
                acc[i][2] += a * bv.z;
                acc[i][3] += a * bv.w;
            }
        }
    }

    #pragma unroll
    for (int i = 0; i < 8; ++i) {
        int row = rowBase + g * 8 + i;
        if (row < n_nodes) {
            float nr = rsqrtf(fmaxf((float)out_deg[row], 1.0f));
            union { __half2 h2[2]; uint2 u; } pk;
            pk.h2[0] = __floats2half2_rn(acc[i][0] * nr, acc[i][1] * nr);
            pk.h2[1] = __floats2half2_rn(acc[i][2] * nr, acc[i][3] * nr);
            *(uint2*)(m + (size_t)row * OUT_DIM + c * 4) = pk.u;
        }
    }
}

// ---------------------------------------------------------------------------
// K6: fused bucket2csr + gather, HALF-BUCKET blocks for load balance.
// Round-4 lesson: 391 blocks on 256 CUs -> 2-blocks-vs-1 CU imbalance +
// 52 KB LDS (3 blocks/CU) gave Occupancy 30%. Now 2 blocks per 256-row
// bucket (782 blocks): each owns 128 rows, filters the parent segment by
// dst-byte bit 7, builds a 20 KB LDS CSR -> ~22 KB LDS total, 4 blocks/CU
// (wave-limited, 32 waves/CU), all 782 blocks co-resident, balanced tail.
// Fast-path guard is exact: post-scan filtered total <= CSR_CAP.
// ---------------------------------------------------------------------------
__global__ void __launch_bounds__(512) bucket_gather_kernel(
        const unsigned* __restrict__ pairs, const int* __restrict__ dbase,
        const __half* __restrict__ m, const float* __restrict__ b,
        float* __restrict__ out, int n_nodes) {
    __shared__ int cnt[GROWS];      // per-row edge count (within half)
    __shared__ int rofs[GROWS];     // inclusive scan of cnt
    __shared__ int cur[GROWS];      // scatter cursor
    __shared__ int csr[CSR_CAP];    // row-sorted src ids (20 KB)

    const int t = threadIdx.x;
    const int bkt = blockIdx.x >> 1;        // parent 256-row bucket
    const int hsel = blockIdx.x & 1;        // which 128-row half
    const unsigned hbit = (unsigned)hsel << 7;
    const int beg = dbase[bkt];
    const int end = dbase[bkt + 1];
    const int rowBase = bkt * BROWS + hsel * GROWS;

    const int wave = t >> 6;
    const int lane = t & 63;
    const int half = lane >> 5;     // which edge of the pair
    const int c    = lane & 31;     // column pair: cols 2c, 2c+1
    const __half2* __restrict__ m2 = (const __half2*)m;   // row stride 32
    const float2 bb = *(const float2*)(b + 2 * c);

    if (t < GROWS) cnt[t] = 0;
    __syncthreads();

    // ---- phase 1: per-row count of this half's edges
    for (int i = beg + t; i < end; i += 512) {
        unsigned p = pairs[i];
        if ((p & 128u) == hbit) atomicAdd(&cnt[p & 127u], 1);
    }
    __syncthreads();
    // ---- phase 2: inclusive scan (Hillis-Steele over 128)
    if (t < GROWS) rofs[t] = cnt[t];
    __syncthreads();
    #pragma unroll
    for (int d = 1; d < GROWS; d <<= 1) {
        int tv = (t < GROWS && t >= d) ? rofs[t - d] : 0;
        __syncthreads();
        if (t < GROWS) rofs[t] += tv;
        __syncthreads();
    }
    if (t < GROWS) cur[t] = rofs[t] - cnt[t];
    __syncthreads();
    const int tot = rofs[GROWS - 1];

    if (tot <= CSR_CAP) {
        // ---- phase 3: position-scatter src ids into LDS CSR (L2-hot re-read)
        for (int i = beg + t; i < end; i += 512) {
            unsigned p = pairs[i];
            if ((p & 128u) == hbit) {
                int pos = atomicAdd(&cur[p & 127u], 1);
                csr[pos] = (int)(p >> 8);
            }
        }
        __syncthreads();
        // ---- phase 4: per-row gather + softmax (16 rows per wave)
        for (int r = wave; r < GROWS; r += 8) {
            const int row = rowBase + r;
            if (row >= n_nodes) continue;          // uniform per wave
            const int cend = rofs[r];
            const int cbeg = cend - cnt[r];
            float ax = 0.f, ay = 0.f;
            int i = cbeg;
            for (; i + 16 <= cend; i += 16) {
                int s[8];
                #pragma unroll
                for (int k = 0; k < 8; ++k) s[k] = csr[i + 2 * k + half];
                #pragma unroll
                for (int k = 0; k < 8; ++k) {
                    float2 f = __half22float2(m2[(unsigned)(s[k] * (OUT_DIM / 2) + c)]);
                    ax += f.x; ay += f.y;
                }
            }
            for (int e = i + half; e < cend; e += 2) {
                float2 f = __half22float2(m2[(unsigned)(csr[e] * (OUT_DIM / 2) + c)]);
                ax += f.x; ay += f.y;
            }
            ax += __shfl_xor(ax, 32, 64);
            ay += __shfl_xor(ay, 32, 64);

            float nd = rsqrtf(fmaxf((float)cnt[r], 1.0f));
            float x0 = ax * nd + bb.x;
            float x1 = ay * nd + bb.y;
            float mx = fmaxf(x0, x1);
            #pragma unroll
            for (int o = 16; o > 0; o >>= 1) mx = fmaxf(mx, __shfl_xor(mx, o, 64));
            float ex0 = expf(x0 - mx), ex1 = expf(x1 - mx);
            float sm = ex0 + ex1;
            #pragma unroll
            for (int o = 16; o > 0; o >>= 1) sm += __shfl_xor(sm, o, 64);
            float ls = logf(sm);
            if (half == 0)
                *(float2*)(out + (size_t)row * OUT_DIM + 2 * c) =
                    make_float2(x0 - mx - ls, x1 - mx - ls);
        }
    } else {
        // ---- slow fallback (pathological half-bucket > CSR_CAP; never on
        // this input): every lane scans the whole parent segment for its rows.
        for (int r = wave; r < GROWS; r += 8) {
            const int row = rowBase + r;
            if (row >= n_nodes) continue;
            const unsigned match = (unsigned)(hsel * GROWS + r);
            float ax = 0.f, ay = 0.f;
            for (int e = beg; e < end; ++e) {
                unsigned p = pairs[e];
                if ((p & 255u) == match) {
                    float2 f = __half22float2(m2[(unsigned)((p >> 8) * (OUT_DIM / 2) + c)]);
                    ax += f.x; ay += f.y;
                }
            }
            // both halves hold full sums: no cross-half combine
            float nd = rsqrtf(fmaxf((float)cnt[r], 1.0f));
            float x0 = ax * nd + bb.x;
            float x1 = ay * nd + bb.y;
            float mx = fmaxf(x0, x1);
            #pragma unroll
            for (int o = 16; o > 0; o >>= 1) mx = fmaxf(mx, __shfl_xor(mx, o, 64));
            float ex0 = expf(x0 - mx), ex1 = expf(x1 - mx);
            float sm = ex0 + ex1;
            #pragma unroll
            for (int o = 16; o > 0; o >>= 1) sm += __shfl_xor(sm, o, 64);
            float ls = logf(sm);
            if (half == 0)
                *(float2*)(out + (size_t)row * OUT_DIM + 2 * c) =
                    make_float2(x0 - mx - ls, x1 - mx - ls);
        }
    }
}

// ---------------------------------------------------------------------------
static inline size_t align16(size_t x) { return (x + 15) & ~(size_t)15; }

extern "C" void kernel_launch(void* const* d_in, const int* in_sizes, int n_in,
                              void* d_out, int out_size, void* d_ws, size_t ws_size,
                              hipStream_t stream) {
    const float* h = (const float*)d_in[0];
    const float* W = (const float*)d_in[1];
    const float* b = (const float*)d_in[2];
    const int* edges = (const int*)d_in[3];

    const int out_dim = in_sizes[2];            // 64
    const int in_dim  = in_sizes[1] / out_dim;  // 256
    const int n_nodes = in_sizes[0] / in_dim;   // 100000
    const int n_edges = in_sizes[3] / 2;        // 3200000

    const int* src = edges;
    const int* dst = edges + n_edges;

    float* out = (float*)d_out;

    const int nb = (n_nodes + BROWS - 1) / BROWS;  // 391 buckets

    // workspace carve-up
    char* ws = (char*)d_ws;
    size_t off = 0;
    int* out_deg     = (int*)(ws + off); off = align16(off + (size_t)n_nodes * 4);
    int* hist2       = (int*)(ws + off); off = align16(off + (size_t)(2 * nb) * 4);
    int* dbase       = (int*)(ws + off); off = align16(off + (size_t)(nb + 1) * 4);
    int* dcursor     = (int*)(ws + off); off = align16(off + (size_t)nb * 4);
    int* sbase       = (int*)(ws + off); off = align16(off + (size_t)(nb + 1) * 4);
    int* scursor     = (int*)(ws + off); off = align16(off + (size_t)nb * 4);
    __half* m        = (__half*)(ws + off); off = align16(off + (size_t)n_nodes * OUT_DIM * 2);
    unsigned* pairs  = (unsigned*)(ws + off); off = align16(off + (size_t)n_edges * 4);
    // sbytes aliases m's storage: written by scatter, consumed by count_src,
    // both strictly before gemm writes m (serial stream ordering).
    // n_edges bytes (3.2 MB) <= n_nodes*OUT_DIM*2 bytes (12.8 MB).
    unsigned char* sbytes = (unsigned char*)m;

    (void)hipMemsetAsync(hist2, 0, (size_t)(2 * nb) * sizeof(int), stream);

    const int hist_blocks = (n_edges + HIST_EDGES - 1) / HIST_EDGES;
    const int sc_blocks   = (n_edges + SC_EDGES - 1) / SC_EDGES;

    hist_kernel<<<hist_blocks, 256, 0, stream>>>(src, dst, hist2, n_edges, nb);
    if (nb + 1 <= 512) {
        scan2_kernel<<<2, 512, 0, stream>>>(hist2, dbase, dcursor, sbase, scursor, nb);
    } else {
        scan_serial_kernel<<<1, 64, 0, stream>>>(hist2, dbase, dcursor, sbase, scursor, nb);
    }
    scatter_pairs_kernel<<<sc_blocks, SC_THREADS, 0, stream>>>(
        src, dst, dcursor, scursor, pairs, sbytes, n_edges, nb);
    count_src_kernel<<<nb, 256, 0, stream>>>(sbytes, sbase, out_deg, n_nodes);

    gemm_kernel<<<(n_nodes + BM - 1) / BM, 256, 0, stream>>>(h, W, out_deg, m, n_nodes);

    bucket_gather_kernel<<<2 * nb, 512, 0, stream>>>(pairs, dbase, m, b, out, n_nodes);
}

// Round 6
// 358.880 us; speedup vs baseline: 4.9136x; 1.0881x over previous
//
#include <hip/hip_runtime.h>
#include <hip/hip_fp16.h>
#include <math.h>

#define IN_DIM 256
#define OUT_DIM 64
#define BROWS 256             // nodes per bucket (pairs format)
#define GROWS 128             // rows per gather block (half bucket)
#define SC_THREADS 512
#define SC_EPB 16
#define SC_EDGES (SC_THREADS * SC_EPB)  // 8192 edges per scatter block
#define BM 128                // gemm rows per block
#define KC 32                 // gemm k-chunk
#define HS_LD 33              // padded leading dim of h tile in LDS
#define CSR_CAP 5120          // LDS CSR capacity per half-bucket (mean 4092, sigma ~64)

// ---------------------------------------------------------------------------
// K1: fused multisplit with fixed-capacity segments + LDS-staged COALESCED
// writes. Replaces round-5's hist+scan+scatter (3 dispatches -> 1):
//  - No histogram/scan pre-pass: every bucket owns a fixed global slot of
//    `cap` entries; per-(block,bucket) chunks are reserved from global
//    cursors (zeroed by memset). Final cursor value = bucket count
//    (consumed by gather / count_src). cap = mean + 22 sigma; OOB clamped.
//  - Write coalescing: block-local exclusive scan over per-bucket counts,
//    stage pairs/bytes bucket-sorted in LDS, then copy out wave-per-bucket
//    run. A run (~21 entries) is contiguous in LDS AND global -> ~20x fewer
//    store requests than per-edge scattered stores.
// ---------------------------------------------------------------------------
__global__ void __launch_bounds__(SC_THREADS) scatter_pairs_kernel(
        const int* __restrict__ src, const int* __restrict__ dst,
        int* __restrict__ dcursor, int* __restrict__ scursor,
        unsigned* __restrict__ pairs, unsigned char* __restrict__ sbytes,
        int n_edges, int nb, int cap) {
    __shared__ int lhd[512];            // dst: per-bucket count (kept)
    __shared__ int lbd[512];            // dst: reserved global base
    __shared__ int lod[512];            // dst: staged offset -> staging cursor -> end
    __shared__ int lhs[512];            // src side, same roles
    __shared__ int lbs[512];
    __shared__ int los[512];
    __shared__ unsigned stp[SC_EDGES];       // staged pairs, 32 KB
    __shared__ unsigned char stb[SC_EDGES];  // staged src bytes, 8 KB

    const int t = threadIdx.x;
    const int wave = t >> 6;
    const int lane = t & 63;

    lhd[t] = 0; lhs[t] = 0;
    __syncthreads();

    // ---- load edges into regs + per-bucket counts
    const int base = blockIdx.x * SC_EDGES;
    int s[SC_EPB], d[SC_EPB];
    if (base + SC_EDGES <= n_edges) {
        const int4* s4 = (const int4*)(src + base);
        const int4* d4 = (const int4*)(dst + base);
        #pragma unroll
        for (int j = 0; j < SC_EPB / 4; ++j) {
            int4 a = s4[j * SC_THREADS + t];
            int4 c = d4[j * SC_THREADS + t];
            s[4*j+0] = a.x; s[4*j+1] = a.y; s[4*j+2] = a.z; s[4*j+3] = a.w;
            d[4*j+0] = c.x; d[4*j+1] = c.y; d[4*j+2] = c.z; d[4*j+3] = c.w;
        }
        #pragma unroll
        for (int i = 0; i < SC_EPB; ++i) {
            atomicAdd(&lhd[d[i] >> 8], 1);
            atomicAdd(&lhs[s[i] >> 8], 1);
        }
    } else {
        #pragma unroll
        for (int i = 0; i < SC_EPB; ++i) {
            int e = base + i * SC_THREADS + t;
            if (e < n_edges) {
                s[i] = src[e];
                d[i] = dst[e];
                atomicAdd(&lhd[d[i] >> 8], 1);
                atomicAdd(&lhs[s[i] >> 8], 1);
            } else {
                s[i] = -1; d[i] = 0;
            }
        }
    }
    __syncthreads();

    // ---- reserve global chunks (one atomic per (block,bucket) per split)
    for (int i = t; i < nb; i += SC_THREADS) {
        int c = lhd[i];
        lbd[i] = c ? atomicAdd(&dcursor[i], c) : 0;
        c = lhs[i];
        lbs[i] = c ? atomicAdd(&scursor[i], c) : 0;
    }

    // ---- block-local exclusive scans (both splits interleaved)
    {
        int vd = (t < nb) ? lhd[t] : 0;
        int vs = (t < nb) ? lhs[t] : 0;
        lod[t] = vd; los[t] = vs;
        __syncthreads();
        #pragma unroll
        for (int dd = 1; dd < 512; dd <<= 1) {
            int td = (t >= dd) ? lod[t - dd] : 0;
            int ts = (t >= dd) ? los[t - dd] : 0;
            __syncthreads();
            lod[t] += td; los[t] += ts;
            __syncthreads();
        }
        lod[t] -= vd; los[t] -= vs;     // own-element: no hazard
    }
    __syncthreads();

    // ---- stage bucket-sorted into LDS (lod/los advance to run ends)
    #pragma unroll
    for (int i = 0; i < SC_EPB; ++i) {
        if (s[i] >= 0) {
            int bkt = d[i] >> 8;
            int pos = atomicAdd(&lod[bkt], 1);
            stp[pos] = ((unsigned)s[i] << 8) | (unsigned)(d[i] & 255);
            int sb = s[i] >> 8;
            int spos = atomicAdd(&los[sb], 1);
            stb[spos] = (unsigned char)(s[i] & 255);
        }
    }
    __syncthreads();

    // ---- coalesced copy-out: wave per bucket run
    for (int b2 = wave; b2 < nb; b2 += SC_THREADS / 64) {
        int cnt = lhd[b2];
        if (cnt) {
            int st = lod[b2] - cnt;           // run start in staging
            int gb = lbd[b2];                 // offset within bucket slot
            unsigned* gp = pairs + (size_t)b2 * cap;
            for (int j = lane; j < cnt; j += 64)
                if (gb + j < cap) gp[gb + j] = stp[st + j];
        }
        cnt = lhs[b2];
        if (cnt) {
            int st = los[b2] - cnt;
            int gb = lbs[b2];
            unsigned char* gp = sbytes + (size_t)b2 * cap;
            for (int j = lane; j < cnt; j += 64)
                if (gb + j < cap) gp[gb + j] = stb[st + j];
        }
    }
}

// ---------------------------------------------------------------------------
// K2: out_deg from src-bucket bytes. One block per src-bucket; LDS count of
// the 256 node slots, coalesced out_deg write. Segment length from scursor.
// ---------------------------------------------------------------------------
__global__ void __launch_bounds__(256) count_src_kernel(
        const unsigned char* __restrict__ sbytes, const int* __restrict__ scursor,
        int* __restrict__ out_deg, int n_nodes, int cap) {
    __shared__ int cnt[BROWS];
    cnt[threadIdx.x] = 0;
    __syncthreads();
    const int beg = blockIdx.x * cap;
    int len = scursor[blockIdx.x];
    if (len > cap) len = cap;
    const int end = beg + len;
    for (int i = beg + threadIdx.x; i < end; i += 256)
        atomicAdd(&cnt[sbytes[i]], 1);
    __syncthreads();
    const int row = blockIdx.x * BROWS + threadIdx.x;
    if (row < n_nodes) out_deg[row] = cnt[threadIdx.x];
}

// ---------------------------------------------------------------------------
// K3: register-tiled GEMM. m[row] = (h[row] @ W) * rsqrt(max(out_deg,1)),
// stored as FP16 (halves the random-gather bytes in K4).
// ---------------------------------------------------------------------------
__global__ void __launch_bounds__(256) gemm_kernel(
        const float* __restrict__ h, const float* __restrict__ W,
        const int* __restrict__ out_deg, __half* __restrict__ m, int n_nodes) {
    __shared__ float hs[BM * HS_LD];       // 16.9 KB
    __shared__ float Ws[KC * OUT_DIM];     // 8 KB

    const int t = threadIdx.x;
    const int c = t & 15;   // col group (4 cols)
    const int g = t >> 4;   // row group (8 rows)
    const int rowBase = blockIdx.x * BM;

    float acc[8][4];
    #pragma unroll
    for (int i = 0; i < 8; ++i)
        #pragma unroll
        for (int j = 0; j < 4; ++j) acc[i][j] = 0.f;

    for (int kc = 0; kc < IN_DIM / KC; ++kc) {
        __syncthreads();
        #pragma unroll
        for (int i = 0; i < 4; ++i) {
            int idx = t + 256 * i;
            int row = idx >> 3;
            int seg = idx & 7;
            int grow = rowBase + row;
            float4 v = make_float4(0.f, 0.f, 0.f, 0.f);
            if (grow < n_nodes)
                v = *(const float4*)(h + (size_t)grow * IN_DIM + kc * KC + seg * 4);
            float* dp = &hs[row * HS_LD + seg * 4];
            dp[0] = v.x; dp[1] = v.y; dp[2] = v.z; dp[3] = v.w;
        }
        {
            const float4* Wg = (const float4*)(W + kc * KC * OUT_DIM);
            float4* Wl = (float4*)Ws;
            Wl[t] = Wg[t];
            Wl[t + 256] = Wg[t + 256];
        }
        __syncthreads();

        #pragma unroll 4
        for (int kk = 0; kk < KC; ++kk) {
            float4 bv = *(const float4*)&Ws[kk * OUT_DIM + c * 4];
            #pragma unroll
            for (int i = 0; i < 8; ++i) {
                float a = hs[(g * 8 + i) * HS_LD + kk];
                acc[i][0] += a * bv.x;
                acc[i][1] += a * bv.y;
                acc[i][2] += a * bv.z;
                acc[i][3] += a * bv.w;
            }
        }
    }

    #pragma unroll
    for (int i = 0; i < 8; ++i) {
        int row = rowBase + g * 8 + i;
        if (row < n_nodes) {
            float nr = rsqrtf(fmaxf((float)out_deg[row], 1.0f));
            union { __half2 h2[2]; uint2 u; } pk;
            pk.h2[0] = __floats2half2_rn(acc[i][0] * nr, acc[i][1] * nr);
            pk.h2[1] = __floats2half2_rn(acc[i][2] * nr, acc[i][3] * nr);
            *(uint2*)(m + (size_t)row * OUT_DIM + c * 4) = pk.u;
        }
    }
}

// ---------------------------------------------------------------------------
// K4: fused bucket2csr + gather, half-bucket blocks (round-5 structure,
// unchanged except segment addressing: beg = bkt*cap, len from dcursor).
// ---------------------------------------------------------------------------
__global__ void __launch_bounds__(512) bucket_gather_kernel(
        const unsigned* __restrict__ pairs, const int* __restrict__ dcursor,
        const __half* __restrict__ m, const float* __restrict__ b,
        float* __restrict__ out, int n_nodes, int cap) {
    __shared__ int cnt[GROWS];      // per-row edge count (within half)
    __shared__ int rofs[GROWS];     // inclusive scan of cnt
    __shared__ int cur[GROWS];      // scatter cursor
    __shared__ int csr[CSR_CAP];    // row-sorted src ids (20 KB)

    const int t = threadIdx.x;
    const int bkt = blockIdx.x >> 1;        // parent 256-row bucket
    const int hsel = blockIdx.x & 1;        // which 128-row half
    const unsigned hbit = (unsigned)hsel << 7;
    const int beg = bkt * cap;
    int len = dcursor[bkt];
    if (len > cap) len = cap;
    const int end = beg + len;
    const int rowBase = bkt * BROWS + hsel * GROWS;

    const int wave = t >> 6;
    const int lane = t & 63;
    const int half = lane >> 5;     // which edge of the pair
    const int c    = lane & 31;     // column pair: cols 2c, 2c+1
    const __half2* __restrict__ m2 = (const __half2*)m;   // row stride 32
    const float2 bb = *(const float2*)(b + 2 * c);

    if (t < GROWS) cnt[t] = 0;
    __syncthreads();

    // ---- phase 1: per-row count of this half's edges
    for (int i = beg + t; i < end; i += 512) {
        unsigned p = pairs[i];
        if ((p & 128u) == hbit) atomicAdd(&cnt[p & 127u], 1);
    }
    __syncthreads();
    // ---- phase 2: inclusive scan (Hillis-Steele over 128)
    if (t < GROWS) rofs[t] = cnt[t];
    __syncthreads();
    #pragma unroll
    for (int d = 1; d < GROWS; d <<= 1) {
        int tv = (t < GROWS && t >= d) ? rofs[t - d] : 0;
        __syncthreads();
        if (t < GROWS) rofs[t] += tv;
        __syncthreads();
    }
    if (t < GROWS) cur[t] = rofs[t] - cnt[t];
    __syncthreads();
    const int tot = rofs[GROWS - 1];

    if (tot <= CSR_CAP) {
        // ---- phase 3: position-scatter src ids into LDS CSR (L2-hot re-read)
        for (int i = beg + t; i < end; i += 512) {
            unsigned p = pairs[i];
            if ((p & 128u) == hbit) {
                int pos = atomicAdd(&cur[p & 127u], 1);
                csr[pos] = (int)(p >> 8);
            }
        }
        __syncthreads();
        // ---- phase 4: per-row gather + softmax (16 rows per wave)
        for (int r = wave; r < GROWS; r += 8) {
            const int row = rowBase + r;
            if (row >= n_nodes) continue;          // uniform per wave
            const int cend = rofs[r];
            const int cbeg = cend - cnt[r];
            float ax = 0.f, ay = 0.f;
            int i = cbeg;
            for (; i + 16 <= cend; i += 16) {
                int s[8];
                #pragma unroll
                for (int k = 0; k < 8; ++k) s[k] = csr[i + 2 * k + half];
                #pragma unroll
                for (int k = 0; k < 8; ++k) {
                    float2 f = __half22float2(m2[(unsigned)(s[k] * (OUT_DIM / 2) + c)]);
                    ax += f.x; ay += f.y;
                }
            }
            for (int e = i + half; e < cend; e += 2) {
                float2 f = __half22float2(m2[(unsigned)(csr[e] * (OUT_DIM / 2) + c)]);
                ax += f.x; ay += f.y;
            }
            ax += __shfl_xor(ax, 32, 64);
            ay += __shfl_xor(ay, 32, 64);

            float nd = rsqrtf(fmaxf((float)cnt[r], 1.0f));
            float x0 = ax * nd + bb.x;
            float x1 = ay * nd + bb.y;
            float mx = fmaxf(x0, x1);
            #pragma unroll
            for (int o = 16; o > 0; o >>= 1) mx = fmaxf(mx, __shfl_xor(mx, o, 64));
            float ex0 = expf(x0 - mx), ex1 = expf(x1 - mx);
            float sm = ex0 + ex1;
            #pragma unroll
            for (int o = 16; o > 0; o >>= 1) sm += __shfl_xor(sm, o, 64);
            float ls = logf(sm);
            if (half == 0)
                *(float2*)(out + (size_t)row * OUT_DIM + 2 * c) =
                    make_float2(x0 - mx - ls, x1 - mx - ls);
        }
    } else {
        // ---- slow fallback (pathological half-bucket > CSR_CAP; never on
        // this input): every lane scans the whole parent segment for its rows.
        for (int r = wave; r < GROWS; r += 8) {
            const int row = rowBase + r;
            if (row >= n_nodes) continue;
            const unsigned match = (unsigned)(hsel * GROWS + r);
            float ax = 0.f, ay = 0.f;
            for (int e = beg; e < end; ++e) {
                unsigned p = pairs[e];
                if ((p & 255u) == match) {
                    float2 f = __half22float2(m2[(unsigned)((p >> 8) * (OUT_DIM / 2) + c)]);
                    ax += f.x; ay += f.y;
                }
            }
            // both halves hold full sums: no cross-half combine
            float nd = rsqrtf(fmaxf((float)cnt[r], 1.0f));
            float x0 = ax * nd + bb.x;
            float x1 = ay * nd + bb.y;
            float mx = fmaxf(x0, x1);
            #pragma unroll
            for (int o = 16; o > 0; o >>= 1) mx = fmaxf(mx, __shfl_xor(mx, o, 64));
            float ex0 = expf(x0 - mx), ex1 = expf(x1 - mx);
            float sm = ex0 + ex1;
            #pragma unroll
            for (int o = 16; o > 0; o >>= 1) sm += __shfl_xor(sm, o, 64);
            float ls = logf(sm);
            if (half == 0)
                *(float2*)(out + (size_t)row * OUT_DIM + 2 * c) =
                    make_float2(x0 - mx - ls, x1 - mx - ls);
        }
    }
}

// ---------------------------------------------------------------------------
static inline size_t align16(size_t x) { return (x + 15) & ~(size_t)15; }

extern "C" void kernel_launch(void* const* d_in, const int* in_sizes, int n_in,
                              void* d_out, int out_size, void* d_ws, size_t ws_size,
                              hipStream_t stream) {
    const float* h = (const float*)d_in[0];
    const float* W = (const float*)d_in[1];
    const float* b = (const float*)d_in[2];
    const int* edges = (const int*)d_in[3];

    const int out_dim = in_sizes[2];            // 64
    const int in_dim  = in_sizes[1] / out_dim;  // 256
    const int n_nodes = in_sizes[0] / in_dim;   // 100000
    const int n_edges = in_sizes[3] / 2;        // 3200000

    const int* src = edges;
    const int* dst = edges + n_edges;

    float* out = (float*)d_out;

    const int nb = (n_nodes + BROWS - 1) / BROWS;  // 391 buckets

    // fixed bucket segment capacity: mean + 25% + 1024, then 1K-align.
    // For this input: mean 8184 -> cap 10240 (~22 sigma headroom).
    const int epb = (n_edges + nb - 1) / nb;
    const int cap = (epb + (epb >> 2) + 1023 + 1023) & ~1023;

    // workspace carve-up
    char* ws = (char*)d_ws;
    size_t off = 0;
    int* out_deg     = (int*)(ws + off); off = align16(off + (size_t)n_nodes * 4);
    int* dcursor     = (int*)(ws + off); off = align16(off + (size_t)nb * 4);
    int* scursor     = (int*)(ws + off); off = align16(off + (size_t)nb * 4);
    __half* m        = (__half*)(ws + off); off = align16(off + (size_t)n_nodes * OUT_DIM * 2);
    unsigned* pairs  = (unsigned*)(ws + off); off = align16(off + (size_t)nb * cap * 4);
    // sbytes aliases m's storage: written by scatter, consumed by count_src,
    // both strictly before gemm writes m (serial stream ordering).
    // nb*cap bytes (4.0 MB) <= n_nodes*OUT_DIM*2 bytes (12.8 MB).
    unsigned char* sbytes = (unsigned char*)m;

    // zero both cursor arrays (contiguous; dcursor start is 16-aligned and
    // nb*4 rounds to the scursor offset)
    (void)hipMemsetAsync(dcursor, 0,
                         (size_t)((char*)(scursor + nb) - (char*)dcursor), stream);

    const int sc_blocks = (n_edges + SC_EDGES - 1) / SC_EDGES;

    scatter_pairs_kernel<<<sc_blocks, SC_THREADS, 0, stream>>>(
        src, dst, dcursor, scursor, pairs, sbytes, n_edges, nb, cap);
    count_src_kernel<<<nb, 256, 0, stream>>>(sbytes, scursor, out_deg, n_nodes, cap);

    gemm_kernel<<<(n_nodes + BM - 1) / BM, 256, 0, stream>>>(h, W, out_deg, m, n_nodes);

    bucket_gather_kernel<<<2 * nb, 512, 0, stream>>>(pairs, dcursor, m, b, out,
                                                     n_nodes, cap);
}

// Round 7
// 358.778 us; speedup vs baseline: 4.9150x; 1.0003x over previous
//
#include <hip/hip_runtime.h>
#include <hip/hip_fp16.h>
#include <math.h>

#define IN_DIM 256
#define OUT_DIM 64
#define BROWS 256             // nodes per bucket (pairs format)
#define GROWS 128             // rows per gather block (half bucket)
#define SC_THREADS 512
#define SC_EPB 16
#define SC_EDGES (SC_THREADS * SC_EPB)  // 8192 edges per scatter block
#define BM 128                // gemm rows per block
#define KC2 64                // gemm k-chunk (fp16 MFMA version)
#define LDH 68                // padded fp16 leading dim (136 B = 17*8, b64-aligned)
#define CSR_CAP 5120          // LDS CSR capacity per half-bucket (mean 4092, sigma ~64)

typedef _Float16 f16x4 __attribute__((ext_vector_type(4)));
typedef float f32x4 __attribute__((ext_vector_type(4)));

// ---------------------------------------------------------------------------
// K1: fused multisplit with fixed-capacity segments + LDS-staged COALESCED
// writes (round-6 version, unchanged).
// ---------------------------------------------------------------------------
__global__ void __launch_bounds__(SC_THREADS) scatter_pairs_kernel(
        const int* __restrict__ src, const int* __restrict__ dst,
        int* __restrict__ dcursor, int* __restrict__ scursor,
        unsigned* __restrict__ pairs, unsigned char* __restrict__ sbytes,
        int n_edges, int nb, int cap) {
    __shared__ int lhd[512];            // dst: per-bucket count (kept)
    __shared__ int lbd[512];            // dst: reserved global base
    __shared__ int lod[512];            // dst: staged offset -> staging cursor -> end
    __shared__ int lhs[512];            // src side, same roles
    __shared__ int lbs[512];
    __shared__ int los[512];
    __shared__ unsigned stp[SC_EDGES];       // staged pairs, 32 KB
    __shared__ unsigned char stb[SC_EDGES];  // staged src bytes, 8 KB

    const int t = threadIdx.x;
    const int wave = t >> 6;
    const int lane = t & 63;

    lhd[t] = 0; lhs[t] = 0;
    __syncthreads();

    // ---- load edges into regs + per-bucket counts
    const int base = blockIdx.x * SC_EDGES;
    int s[SC_EPB], d[SC_EPB];
    if (base + SC_EDGES <= n_edges) {
        const int4* s4 = (const int4*)(src + base);
        const int4* d4 = (const int4*)(dst + base);
        #pragma unroll
        for (int j = 0; j < SC_EPB / 4; ++j) {
            int4 a = s4[j * SC_THREADS + t];
            int4 c = d4[j * SC_THREADS + t];
            s[4*j+0] = a.x; s[4*j+1] = a.y; s[4*j+2] = a.z; s[4*j+3] = a.w;
            d[4*j+0] = c.x; d[4*j+1] = c.y; d[4*j+2] = c.z; d[4*j+3] = c.w;
        }
        #pragma unroll
        for (int i = 0; i < SC_EPB; ++i) {
            atomicAdd(&lhd[d[i] >> 8], 1);
            atomicAdd(&lhs[s[i] >> 8], 1);
        }
    } else {
        #pragma unroll
        for (int i = 0; i < SC_EPB; ++i) {
            int e = base + i * SC_THREADS + t;
            if (e < n_edges) {
                s[i] = src[e];
                d[i] = dst[e];
                atomicAdd(&lhd[d[i] >> 8], 1);
                atomicAdd(&lhs[s[i] >> 8], 1);
            } else {
                s[i] = -1; d[i] = 0;
            }
        }
    }
    __syncthreads();

    // ---- reserve global chunks (one atomic per (block,bucket) per split)
    for (int i = t; i < nb; i += SC_THREADS) {
        int c = lhd[i];
        lbd[i] = c ? atomicAdd(&dcursor[i], c) : 0;
        c = lhs[i];
        lbs[i] = c ? atomicAdd(&scursor[i], c) : 0;
    }

    // ---- block-local exclusive scans (both splits interleaved)
    {
        int vd = (t < nb) ? lhd[t] : 0;
        int vs = (t < nb) ? lhs[t] : 0;
        lod[t] = vd; los[t] = vs;
        __syncthreads();
        #pragma unroll
        for (int dd = 1; dd < 512; dd <<= 1) {
            int td = (t >= dd) ? lod[t - dd] : 0;
            int ts = (t >= dd) ? los[t - dd] : 0;
            __syncthreads();
            lod[t] += td; los[t] += ts;
            __syncthreads();
        }
        lod[t] -= vd; los[t] -= vs;     // own-element: no hazard
    }
    __syncthreads();

    // ---- stage bucket-sorted into LDS (lod/los advance to run ends)
    #pragma unroll
    for (int i = 0; i < SC_EPB; ++i) {
        if (s[i] >= 0) {
            int bkt = d[i] >> 8;
            int pos = atomicAdd(&lod[bkt], 1);
            stp[pos] = ((unsigned)s[i] << 8) | (unsigned)(d[i] & 255);
            int sb = s[i] >> 8;
            int spos = atomicAdd(&los[sb], 1);
            stb[spos] = (unsigned char)(s[i] & 255);
        }
    }
    __syncthreads();

    // ---- coalesced copy-out: wave per bucket run
    for (int b2 = wave; b2 < nb; b2 += SC_THREADS / 64) {
        int cnt = lhd[b2];
        if (cnt) {
            int st = lod[b2] - cnt;           // run start in staging
            int gb = lbd[b2];                 // offset within bucket slot
            unsigned* gp = pairs + (size_t)b2 * cap;
            for (int j = lane; j < cnt; j += 64)
                if (gb + j < cap) gp[gb + j] = stp[st + j];
        }
        cnt = lhs[b2];
        if (cnt) {
            int st = los[b2] - cnt;
            int gb = lbs[b2];
            unsigned char* gp = sbytes + (size_t)b2 * cap;
            for (int j = lane; j < cnt; j += 64)
                if (gb + j < cap) gp[gb + j] = stb[st + j];
        }
    }
}

// ---------------------------------------------------------------------------
// K2: out_deg from src-bucket bytes (round-6 version, unchanged).
// ---------------------------------------------------------------------------
__global__ void __launch_bounds__(256) count_src_kernel(
        const unsigned char* __restrict__ sbytes, const int* __restrict__ scursor,
        int* __restrict__ out_deg, int n_nodes, int cap) {
    __shared__ int cnt[BROWS];
    cnt[threadIdx.x] = 0;
    __syncthreads();
    const int beg = blockIdx.x * cap;
    int len = scursor[blockIdx.x];
    if (len > cap) len = cap;
    const int end = beg + len;
    for (int i = beg + threadIdx.x; i < end; i += 256)
        atomicAdd(&cnt[sbytes[i]], 1);
    __syncthreads();
    const int row = blockIdx.x * BROWS + threadIdx.x;
    if (row < n_nodes) out_deg[row] = cnt[threadIdx.x];
}

// ---------------------------------------------------------------------------
// K3: MFMA GEMM (fp16 in, fp32 accumulate). m[row] = (h[row]@W)*ns[row], fp16.
// Round-6's VALU gemm was LDS-read-bound (~2048 scalar ds_read per thread).
// Now: v_mfma_f32_16x16x16_f16, operand-SWAPPED (A = W^T frag, B = h frag)
// so each lane's D holds 4 consecutive OUTPUT COLS of one node row ->
// packed 8 B fp16 store, no epilogue transpose.
// Layouts (doc-verified classic shape): A[m=l%16][k=4*(l/16)+j],
// B[k=4*(l/16)+j][n=l%16], D[m=4*(l/16)+r][n=l%16].
// Per wave: 2 row-tiles x 4 col-tiles; per 16-k step: 6 ds_read_b64 + 8 MFMA.
// LDS ~26 KB; kernel becomes h-streaming bound (~102 MB read -> ~25 us).
// ---------------------------------------------------------------------------
__global__ void __launch_bounds__(256) gemm_kernel(
        const float* __restrict__ h, const float* __restrict__ W,
        const int* __restrict__ out_deg, __half* __restrict__ m, int n_nodes) {
    __shared__ _Float16 hs[BM * LDH];        // 128 x 68 fp16 = 17.4 KB
    __shared__ _Float16 Wt[OUT_DIM * LDH];   // 64 x 68 fp16 = 8.7 KB (transposed)

    const int t = threadIdx.x;
    const int wave = t >> 6;
    const int lane = t & 63;
    const int lg = lane >> 4;       // k-subgroup / D col-subgroup
    const int li = lane & 15;       // A-row (out col) / B-col (node row)
    const int rowBase = blockIdx.x * BM;

    f32x4 acc[2][4];
    #pragma unroll
    for (int rt = 0; rt < 2; ++rt)
        #pragma unroll
        for (int ct = 0; ct < 4; ++ct)
            acc[rt][ct] = (f32x4){0.f, 0.f, 0.f, 0.f};

    for (int kc = 0; kc < IN_DIM / KC2; ++kc) {
        __syncthreads();
        // ---- stage hs: 128 rows x 64 k, fp32 -> fp16 (float4 loads)
        #pragma unroll
        for (int i = 0; i < 8; ++i) {
            int idx = t + 256 * i;          // 2048 float4s
            int row = idx >> 4;             // 16 float4 per row
            int s4 = idx & 15;
            float4 v = make_float4(0.f, 0.f, 0.f, 0.f);
            if (rowBase + row < n_nodes)
                v = *(const float4*)(h + (size_t)(rowBase + row) * IN_DIM
                                     + kc * KC2 + s4 * 4);
            _Float16* dp = &hs[row * LDH + s4 * 4];
            dp[0] = (_Float16)v.x; dp[1] = (_Float16)v.y;
            dp[2] = (_Float16)v.z; dp[3] = (_Float16)v.w;
        }
        // ---- stage Wt transposed: Wt[n][k] = W[kc*64+k][n], fp32 -> fp16
        #pragma unroll
        for (int i = 0; i < 16; ++i) {
            int idx = t + 256 * i;          // 4096 elems
            int k = idx >> 6;
            int n = idx & 63;
            Wt[n * LDH + k] = (_Float16)W[(size_t)(kc * KC2 + k) * OUT_DIM + n];
        }
        __syncthreads();

        #pragma unroll
        for (int ks = 0; ks < KC2 / 16; ++ks) {
            const int k0 = ks * 16 + lg * 4;
            // B-frags: 2 node-row tiles owned by this wave
            f16x4 b0 = *(const f16x4*)&hs[((wave * 2 + 0) * 16 + li) * LDH + k0];
            f16x4 b1 = *(const f16x4*)&hs[((wave * 2 + 1) * 16 + li) * LDH + k0];
            // A-frags: 4 output-col tiles
            f16x4 a0 = *(const f16x4*)&Wt[(0 * 16 + li) * LDH + k0];
            f16x4 a1 = *(const f16x4*)&Wt[(1 * 16 + li) * LDH + k0];
            f16x4 a2 = *(const f16x4*)&Wt[(2 * 16 + li) * LDH + k0];
            f16x4 a3 = *(const f16x4*)&Wt[(3 * 16 + li) * LDH + k0];
            acc[0][0] = __builtin_amdgcn_mfma_f32_16x16x16f16(a0, b0, acc[0][0], 0, 0, 0);
            acc[0][1] = __builtin_amdgcn_mfma_f32_16x16x16f16(a1, b0, acc[0][1], 0, 0, 0);
            acc[0][2] = __builtin_amdgcn_mfma_f32_16x16x16f16(a2, b0, acc[0][2], 0, 0, 0);
            acc[0][3] = __builtin_amdgcn_mfma_f32_16x16x16f16(a3, b0, acc[0][3], 0, 0, 0);
            acc[1][0] = __builtin_amdgcn_mfma_f32_16x16x16f16(a0, b1, acc[1][0], 0, 0, 0);
            acc[1][1] = __builtin_amdgcn_mfma_f32_16x16x16f16(a1, b1, acc[1][1], 0, 0, 0);
            acc[1][2] = __builtin_amdgcn_mfma_f32_16x16x16f16(a2, b1, acc[1][2], 0, 0, 0);
            acc[1][3] = __builtin_amdgcn_mfma_f32_16x16x16f16(a3, b1, acc[1][3], 0, 0, 0);
        }
    }

    // ---- epilogue: lane holds cols {ct*16 + lg*4 + r} of node row
    // rowBase + (wave*2+rt)*16 + li -> one packed uint2 (4 fp16) per tile.
    #pragma unroll
    for (int rt = 0; rt < 2; ++rt) {
        int row = rowBase + (wave * 2 + rt) * 16 + li;
        if (row < n_nodes) {
            float nr = rsqrtf(fmaxf((float)out_deg[row], 1.0f));
            #pragma unroll
            for (int ct = 0; ct < 4; ++ct) {
                f32x4 dv = acc[rt][ct];
                union { __half2 h2[2]; uint2 u; } pk;
                pk.h2[0] = __floats2half2_rn(dv[0] * nr, dv[1] * nr);
                pk.h2[1] = __floats2half2_rn(dv[2] * nr, dv[3] * nr);
                *(uint2*)(m + (size_t)row * OUT_DIM + ct * 16 + lg * 4) = pk.u;
            }
        }
    }
}

// ---------------------------------------------------------------------------
// K4: fused bucket2csr + gather, half-bucket blocks (round-6 version,
// unchanged).
// ---------------------------------------------------------------------------
__global__ void __launch_bounds__(512) bucket_gather_kernel(
        const unsigned* __restrict__ pairs, const int* __restrict__ dcursor,
        const __half* __restrict__ m, const float* __restrict__ b,
        float* __restrict__ out, int n_nodes, int cap) {
    __shared__ int cnt[GROWS];      // per-row edge count (within half)
    __shared__ int rofs[GROWS];     // inclusive scan of cnt
    __shared__ int cur[GROWS];      // scatter cursor
    __shared__ int csr[CSR_CAP];    // row-sorted src ids (20 KB)

    const int t = threadIdx.x;
    const int bkt = blockIdx.x >> 1;        // parent 256-row bucket
    const int hsel = blockIdx.x & 1;        // which 128-row half
    const unsigned hbit = (unsigned)hsel << 7;
    const int beg = bkt * cap;
    int len = dcursor[bkt];
    if (len > cap) len = cap;
    const int end = beg + len;
    const int rowBase = bkt * BROWS + hsel * GROWS;

    const int wave = t >> 6;
    const int lane = t & 63;
    const int half = lane >> 5;     // which edge of the pair
    const int c    = lane & 31;     // column pair: cols 2c, 2c+1
    const __half2* __restrict__ m2 = (const __half2*)m;   // row stride 32
    const float2 bb = *(const float2*)(b + 2 * c);

    if (t < GROWS) cnt[t] = 0;
    __syncthreads();

    // ---- phase 1: per-row count of this half's edges
    for (int i = beg + t; i < end; i += 512) {
        unsigned p = pairs[i];
        if ((p & 128u) == hbit) atomicAdd(&cnt[p & 127u], 1);
    }
    __syncthreads();
    // ---- phase 2: inclusive scan (Hillis-Steele over 128)
    if (t < GROWS) rofs[t] = cnt[t];
    __syncthreads();
    #pragma unroll
    for (int d = 1; d < GROWS; d <<= 1) {
        int tv = (t < GROWS && t >= d) ? rofs[t - d] : 0;
        __syncthreads();
        if (t < GROWS) rofs[t] += tv;
        __syncthreads();
    }
    if (t < GROWS) cur[t] = rofs[t] - cnt[t];
    __syncthreads();
    const int tot = rofs[GROWS - 1];

    if (tot <= CSR_CAP) {
        // ---- phase 3: position-scatter src ids into LDS CSR (L2-hot re-read)
        for (int i = beg + t; i < end; i += 512) {
            unsigned p = pairs[i];
            if ((p & 128u) == hbit) {
                int pos = atomicAdd(&cur[p & 127u], 1);
                csr[pos] = (int)(p >> 8);
            }
        }
        __syncthreads();
        // ---- phase 4: per-row gather + softmax (16 rows per wave)
        for (int r = wave; r < GROWS; r += 8) {
            const int row = rowBase + r;
            if (row >= n_nodes) continue;          // uniform per wave
            const int cend = rofs[r];
            const int cbeg = cend - cnt[r];
            float ax = 0.f, ay = 0.f;
            int i = cbeg;
            for (; i + 16 <= cend; i += 16) {
                int s[8];
                #pragma unroll
                for (int k = 0; k < 8; ++k) s[k] = csr[i + 2 * k + half];
                #pragma unroll
                for (int k = 0; k < 8; ++k) {
                    float2 f = __half22float2(m2[(unsigned)(s[k] * (OUT_DIM / 2) + c)]);
                    ax += f.x; ay += f.y;
                }
            }
            for (int e = i + half; e < cend; e += 2) {
                float2 f = __half22float2(m2[(unsigned)(csr[e] * (OUT_DIM / 2) + c)]);
                ax += f.x; ay += f.y;
            }
            ax += __shfl_xor(ax, 32, 64);
            ay += __shfl_xor(ay, 32, 64);

            float nd = rsqrtf(fmaxf((float)cnt[r], 1.0f));
            float x0 = ax * nd + bb.x;
            float x1 = ay * nd + bb.y;
            float mx = fmaxf(x0, x1);
            #pragma unroll
            for (int o = 16; o > 0; o >>= 1) mx = fmaxf(mx, __shfl_xor(mx, o, 64));
            float ex0 = expf(x0 - mx), ex1 = expf(x1 - mx);
            float sm = ex0 + ex1;
            #pragma unroll
            for (int o = 16; o > 0; o >>= 1) sm += __shfl_xor(sm, o, 64);
            float ls = logf(sm);
            if (half == 0)
                *(float2*)(out + (size_t)row * OUT_DIM + 2 * c) =
                    make_float2(x0 - mx - ls, x1 - mx - ls);
        }
    } else {
        // ---- slow fallback (pathological half-bucket > CSR_CAP; never on
        // this input): every lane scans the whole parent segment for its rows.
        for (int r = wave; r < GROWS; r += 8) {
            const int row = rowBase + r;
            if (row >= n_nodes) continue;
            const unsigned match = (unsigned)(hsel * GROWS + r);
            float ax = 0.f, ay = 0.f;
            for (int e = beg; e < end; ++e) {
                unsigned p = pairs[e];
                if ((p & 255u) == match) {
                    float2 f = __half22float2(m2[(unsigned)((p >> 8) * (OUT_DIM / 2) + c)]);
                    ax += f.x; ay += f.y;
                }
            }
            // both halves hold full sums: no cross-half combine
            float nd = rsqrtf(fmaxf((float)cnt[r], 1.0f));
            float x0 = ax * nd + bb.x;
            float x1 = ay * nd + bb.y;
            float mx = fmaxf(x0, x1);
            #pragma unroll
            for (int o = 16; o > 0; o >>= 1) mx = fmaxf(mx, __shfl_xor(mx, o, 64));
            float ex0 = expf(x0 - mx), ex1 = expf(x1 - mx);
            float sm = ex0 + ex1;
            #pragma unroll
            for (int o = 16; o > 0; o >>= 1) sm += __shfl_xor(sm, o, 64);
            float ls = logf(sm);
            if (half == 0)
                *(float2*)(out + (size_t)row * OUT_DIM + 2 * c) =
                    make_float2(x0 - mx - ls, x1 - mx - ls);
        }
    }
}

// ---------------------------------------------------------------------------
static inline size_t align16(size_t x) { return (x + 15) & ~(size_t)15; }

extern "C" void kernel_launch(void* const* d_in, const int* in_sizes, int n_in,
                              void* d_out, int out_size, void* d_ws, size_t ws_size,
                              hipStream_t stream) {
    const float* h = (const float*)d_in[0];
    const float* W = (const float*)d_in[1];
    const float* b = (const float*)d_in[2];
    const int* edges = (const int*)d_in[3];

    const int out_dim = in_sizes[2];            // 64
    const int in_dim  = in_sizes[1] / out_dim;  // 256
    const int n_nodes = in_sizes[0] / in_dim;   // 100000
    const int n_edges = in_sizes[3] / 2;        // 3200000

    const int* src = edges;
    const int* dst = edges + n_edges;

    float* out = (float*)d_out;

    const int nb = (n_nodes + BROWS - 1) / BROWS;  // 391 buckets

    // fixed bucket segment capacity: mean + 25% + 1024, then 1K-align.
    // For this input: mean 8184 -> cap 10240 (~22 sigma headroom).
    const int epb = (n_edges + nb - 1) / nb;
    const int cap = (epb + (epb >> 2) + 1023 + 1023) & ~1023;

    // workspace carve-up
    char* ws = (char*)d_ws;
    size_t off = 0;
    int* out_deg     = (int*)(ws + off); off = align16(off + (size_t)n_nodes * 4);
    int* dcursor     = (int*)(ws + off); off = align16(off + (size_t)nb * 4);
    int* scursor     = (int*)(ws + off); off = align16(off + (size_t)nb * 4);
    __half* m        = (__half*)(ws + off); off = align16(off + (size_t)n_nodes * OUT_DIM * 2);
    unsigned* pairs  = (unsigned*)(ws + off); off = align16(off + (size_t)nb * cap * 4);
    // sbytes aliases m's storage: written by scatter, consumed by count_src,
    // both strictly before gemm writes m (serial stream ordering).
    // nb*cap bytes (4.0 MB) <= n_nodes*OUT_DIM*2 bytes (12.8 MB).
    unsigned char* sbytes = (unsigned char*)m;

    // zero both cursor arrays (contiguous)
    (void)hipMemsetAsync(dcursor, 0,
                         (size_t)((char*)(scursor + nb) - (char*)dcursor), stream);

    const int sc_blocks = (n_edges + SC_EDGES - 1) / SC_EDGES;

    scatter_pairs_kernel<<<sc_blocks, SC_THREADS, 0, stream>>>(
        src, dst, dcursor, scursor, pairs, sbytes, n_edges, nb, cap);
    count_src_kernel<<<nb, 256, 0, stream>>>(sbytes, scursor, out_deg, n_nodes, cap);

    gemm_kernel<<<(n_nodes + BM - 1) / BM, 256, 0, stream>>>(h, W, out_deg, m, n_nodes);

    bucket_gather_kernel<<<2 * nb, 512, 0, stream>>>(pairs, dcursor, m, b, out,
                                                     n_nodes, cap);
}

// Round 8
// 358.379 us; speedup vs baseline: 4.9204x; 1.0011x over previous
//
#include <hip/hip_runtime.h>
#include <hip/hip_fp16.h>
#include <math.h>

#define IN_DIM 256
#define OUT_DIM 64
#define BROWS 256             // nodes per bucket (pairs format)
#define GROWS 128             // rows per gather block (half bucket)
#define SC_THREADS 512
#define SC_EPB 16
#define SC_EDGES (SC_THREADS * SC_EPB)  // 8192 edges per scatter block
#define BM 128                // gemm rows per block
#define KC2 64                // gemm k-chunk (fp16 MFMA version)
#define LDH 68                // padded fp16 leading dim (136 B = 17*8, b64-aligned)
#define CSR_CAP 5120          // LDS CSR capacity per half-bucket (mean 4092, sigma ~64)

typedef _Float16 f16x4 __attribute__((ext_vector_type(4)));
typedef float f32x4 __attribute__((ext_vector_type(4)));

// ---------------------------------------------------------------------------
// K1: fused multisplit with fixed-capacity segments + LDS-staged COALESCED
// writes (round-6 version, unchanged).
// ---------------------------------------------------------------------------
__global__ void __launch_bounds__(SC_THREADS) scatter_pairs_kernel(
        const int* __restrict__ src, const int* __restrict__ dst,
        int* __restrict__ dcursor, int* __restrict__ scursor,
        unsigned* __restrict__ pairs, unsigned char* __restrict__ sbytes,
        int n_edges, int nb, int cap) {
    __shared__ int lhd[512];            // dst: per-bucket count (kept)
    __shared__ int lbd[512];            // dst: reserved global base
    __shared__ int lod[512];            // dst: staged offset -> staging cursor -> end
    __shared__ int lhs[512];            // src side, same roles
    __shared__ int lbs[512];
    __shared__ int los[512];
    __shared__ unsigned stp[SC_EDGES];       // staged pairs, 32 KB
    __shared__ unsigned char stb[SC_EDGES];  // staged src bytes, 8 KB

    const int t = threadIdx.x;
    const int wave = t >> 6;
    const int lane = t & 63;

    lhd[t] = 0; lhs[t] = 0;
    __syncthreads();

    // ---- load edges into regs + per-bucket counts
    const int base = blockIdx.x * SC_EDGES;
    int s[SC_EPB], d[SC_EPB];
    if (base + SC_EDGES <= n_edges) {
        const int4* s4 = (const int4*)(src + base);
        const int4* d4 = (const int4*)(dst + base);
        #pragma unroll
        for (int j = 0; j < SC_EPB / 4; ++j) {
            int4 a = s4[j * SC_THREADS + t];
            int4 c = d4[j * SC_THREADS + t];
            s[4*j+0] = a.x; s[4*j+1] = a.y; s[4*j+2] = a.z; s[4*j+3] = a.w;
            d[4*j+0] = c.x; d[4*j+1] = c.y; d[4*j+2] = c.z; d[4*j+3] = c.w;
        }
        #pragma unroll
        for (int i = 0; i < SC_EPB; ++i) {
            atomicAdd(&lhd[d[i] >> 8], 1);
            atomicAdd(&lhs[s[i] >> 8], 1);
        }
    } else {
        #pragma unroll
        for (int i = 0; i < SC_EPB; ++i) {
            int e = base + i * SC_THREADS + t;
            if (e < n_edges) {
                s[i] = src[e];
                d[i] = dst[e];
                atomicAdd(&lhd[d[i] >> 8], 1);
                atomicAdd(&lhs[s[i] >> 8], 1);
            } else {
                s[i] = -1; d[i] = 0;
            }
        }
    }
    __syncthreads();

    // ---- reserve global chunks (one atomic per (block,bucket) per split)
    for (int i = t; i < nb; i += SC_THREADS) {
        int c = lhd[i];
        lbd[i] = c ? atomicAdd(&dcursor[i], c) : 0;
        c = lhs[i];
        lbs[i] = c ? atomicAdd(&scursor[i], c) : 0;
    }

    // ---- block-local exclusive scans (both splits interleaved)
    {
        int vd = (t < nb) ? lhd[t] : 0;
        int vs = (t < nb) ? lhs[t] : 0;
        lod[t] = vd; los[t] = vs;
        __syncthreads();
        #pragma unroll
        for (int dd = 1; dd < 512; dd <<= 1) {
            int td = (t >= dd) ? lod[t - dd] : 0;
            int ts = (t >= dd) ? los[t - dd] : 0;
            __syncthreads();
            lod[t] += td; los[t] += ts;
            __syncthreads();
        }
        lod[t] -= vd; los[t] -= vs;     // own-element: no hazard
    }
    __syncthreads();

    // ---- stage bucket-sorted into LDS (lod/los advance to run ends)
    #pragma unroll
    for (int i = 0; i < SC_EPB; ++i) {
        if (s[i] >= 0) {
            int bkt = d[i] >> 8;
            int pos = atomicAdd(&lod[bkt], 1);
            stp[pos] = ((unsigned)s[i] << 8) | (unsigned)(d[i] & 255);
            int sb = s[i] >> 8;
            int spos = atomicAdd(&los[sb], 1);
            stb[spos] = (unsigned char)(s[i] & 255);
        }
    }
    __syncthreads();

    // ---- coalesced copy-out: wave per bucket run
    for (int b2 = wave; b2 < nb; b2 += SC_THREADS / 64) {
        int cnt = lhd[b2];
        if (cnt) {
            int st = lod[b2] - cnt;           // run start in staging
            int gb = lbd[b2];                 // offset within bucket slot
            unsigned* gp = pairs + (size_t)b2 * cap;
            for (int j = lane; j < cnt; j += 64)
                if (gb + j < cap) gp[gb + j] = stp[st + j];
        }
        cnt = lhs[b2];
        if (cnt) {
            int st = los[b2] - cnt;
            int gb = lbs[b2];
            unsigned char* gp = sbytes + (size_t)b2 * cap;
            for (int j = lane; j < cnt; j += 64)
                if (gb + j < cap) gp[gb + j] = stb[st + j];
        }
    }
}

// ---------------------------------------------------------------------------
// K2: out_deg from src-bucket bytes (round-6 version, unchanged).
// ---------------------------------------------------------------------------
__global__ void __launch_bounds__(256) count_src_kernel(
        const unsigned char* __restrict__ sbytes, const int* __restrict__ scursor,
        int* __restrict__ out_deg, int n_nodes, int cap) {
    __shared__ int cnt[BROWS];
    cnt[threadIdx.x] = 0;
    __syncthreads();
    const int beg = blockIdx.x * cap;
    int len = scursor[blockIdx.x];
    if (len > cap) len = cap;
    const int end = beg + len;
    for (int i = beg + threadIdx.x; i < end; i += 256)
        atomicAdd(&cnt[sbytes[i]], 1);
    __syncthreads();
    const int row = blockIdx.x * BROWS + threadIdx.x;
    if (row < n_nodes) out_deg[row] = cnt[threadIdx.x];
}

// ---------------------------------------------------------------------------
// K3: MFMA GEMM (round-7 version, unchanged). fp16 in, fp32 accumulate,
// operand-swapped so each lane's D = 4 consecutive output cols of one row.
// ---------------------------------------------------------------------------
__global__ void __launch_bounds__(256) gemm_kernel(
        const float* __restrict__ h, const float* __restrict__ W,
        const int* __restrict__ out_deg, __half* __restrict__ m, int n_nodes) {
    __shared__ _Float16 hs[BM * LDH];        // 128 x 68 fp16 = 17.4 KB
    __shared__ _Float16 Wt[OUT_DIM * LDH];   // 64 x 68 fp16 = 8.7 KB (transposed)

    const int t = threadIdx.x;
    const int wave = t >> 6;
    const int lane = t & 63;
    const int lg = lane >> 4;       // k-subgroup / D col-subgroup
    const int li = lane & 15;       // A-row (out col) / B-col (node row)
    const int rowBase = blockIdx.x * BM;

    f32x4 acc[2][4];
    #pragma unroll
    for (int rt = 0; rt < 2; ++rt)
        #pragma unroll
        for (int ct = 0; ct < 4; ++ct)
            acc[rt][ct] = (f32x4){0.f, 0.f, 0.f, 0.f};

    for (int kc = 0; kc < IN_DIM / KC2; ++kc) {
        __syncthreads();
        // ---- stage hs: 128 rows x 64 k, fp32 -> fp16 (float4 loads)
        #pragma unroll
        for (int i = 0; i < 8; ++i) {
            int idx = t + 256 * i;          // 2048 float4s
            int row = idx >> 4;             // 16 float4 per row
            int s4 = idx & 15;
            float4 v = make_float4(0.f, 0.f, 0.f, 0.f);
            if (rowBase + row < n_nodes)
                v = *(const float4*)(h + (size_t)(rowBase + row) * IN_DIM
                                     + kc * KC2 + s4 * 4);
            _Float16* dp = &hs[row * LDH + s4 * 4];
            dp[0] = (_Float16)v.x; dp[1] = (_Float16)v.y;
            dp[2] = (_Float16)v.z; dp[3] = (_Float16)v.w;
        }
        // ---- stage Wt transposed: Wt[n][k] = W[kc*64+k][n], fp32 -> fp16
        #pragma unroll
        for (int i = 0; i < 16; ++i) {
            int idx = t + 256 * i;          // 4096 elems
            int k = idx >> 6;
            int n = idx & 63;
            Wt[n * LDH + k] = (_Float16)W[(size_t)(kc * KC2 + k) * OUT_DIM + n];
        }
        __syncthreads();

        #pragma unroll
        for (int ks = 0; ks < KC2 / 16; ++ks) {
            const int k0 = ks * 16 + lg * 4;
            f16x4 b0 = *(const f16x4*)&hs[((wave * 2 + 0) * 16 + li) * LDH + k0];
            f16x4 b1 = *(const f16x4*)&hs[((wave * 2 + 1) * 16 + li) * LDH + k0];
            f16x4 a0 = *(const f16x4*)&Wt[(0 * 16 + li) * LDH + k0];
            f16x4 a1 = *(const f16x4*)&Wt[(1 * 16 + li) * LDH + k0];
            f16x4 a2 = *(const f16x4*)&Wt[(2 * 16 + li) * LDH + k0];
            f16x4 a3 = *(const f16x4*)&Wt[(3 * 16 + li) * LDH + k0];
            acc[0][0] = __builtin_amdgcn_mfma_f32_16x16x16f16(a0, b0, acc[0][0], 0, 0, 0);
            acc[0][1] = __builtin_amdgcn_mfma_f32_16x16x16f16(a1, b0, acc[0][1], 0, 0, 0);
            acc[0][2] = __builtin_amdgcn_mfma_f32_16x16x16f16(a2, b0, acc[0][2], 0, 0, 0);
            acc[0][3] = __builtin_amdgcn_mfma_f32_16x16x16f16(a3, b0, acc[0][3], 0, 0, 0);
            acc[1][0] = __builtin_amdgcn_mfma_f32_16x16x16f16(a0, b1, acc[1][0], 0, 0, 0);
            acc[1][1] = __builtin_amdgcn_mfma_f32_16x16x16f16(a1, b1, acc[1][1], 0, 0, 0);
            acc[1][2] = __builtin_amdgcn_mfma_f32_16x16x16f16(a2, b1, acc[1][2], 0, 0, 0);
            acc[1][3] = __builtin_amdgcn_mfma_f32_16x16x16f16(a3, b1, acc[1][3], 0, 0, 0);
        }
    }

    #pragma unroll
    for (int rt = 0; rt < 2; ++rt) {
        int row = rowBase + (wave * 2 + rt) * 16 + li;
        if (row < n_nodes) {
            float nr = rsqrtf(fmaxf((float)out_deg[row], 1.0f));
            #pragma unroll
            for (int ct = 0; ct < 4; ++ct) {
                f32x4 dv = acc[rt][ct];
                union { __half2 h2[2]; uint2 u; } pk;
                pk.h2[0] = __floats2half2_rn(dv[0] * nr, dv[1] * nr);
                pk.h2[1] = __floats2half2_rn(dv[2] * nr, dv[3] * nr);
                *(uint2*)(m + (size_t)row * OUT_DIM + ct * 16 + lg * 4) = pk.u;
            }
        }
    }
}

// ---------------------------------------------------------------------------
// K4: fused bucket2csr + gather, half-bucket blocks. Phase 4 now processes
// TWO ROWS PER WAVE interleaved (r, r+8): 16 independent half2 gathers in
// flight per lane even at typical degree ~32 (vs 8 before, exhausted after
// ~2 batches/row). Same per-row accumulation order -> bitwise-identical
// output. Phases 1-3 unchanged.
// ---------------------------------------------------------------------------
__global__ void __launch_bounds__(512) bucket_gather_kernel(
        const unsigned* __restrict__ pairs, const int* __restrict__ dcursor,
        const __half* __restrict__ m, const float* __restrict__ b,
        float* __restrict__ out, int n_nodes, int cap) {
    __shared__ int cnt[GROWS];      // per-row edge count (within half)
    __shared__ int rofs[GROWS];     // inclusive scan of cnt
    __shared__ int cur[GROWS];      // scatter cursor
    __shared__ int csr[CSR_CAP];    // row-sorted src ids (20 KB)

    const int t = threadIdx.x;
    const int bkt = blockIdx.x >> 1;        // parent 256-row bucket
    const int hsel = blockIdx.x & 1;        // which 128-row half
    const unsigned hbit = (unsigned)hsel << 7;
    const int beg = bkt * cap;
    int len = dcursor[bkt];
    if (len > cap) len = cap;
    const int end = beg + len;
    const int rowBase = bkt * BROWS + hsel * GROWS;

    const int wave = t >> 6;
    const int lane = t & 63;
    const int half = lane >> 5;     // which edge of the pair
    const int c    = lane & 31;     // column pair: cols 2c, 2c+1
    const __half2* __restrict__ m2 = (const __half2*)m;   // row stride 32
    const float2 bb = *(const float2*)(b + 2 * c);

    if (t < GROWS) cnt[t] = 0;
    __syncthreads();

    // ---- phase 1: per-row count of this half's edges
    for (int i = beg + t; i < end; i += 512) {
        unsigned p = pairs[i];
        if ((p & 128u) == hbit) atomicAdd(&cnt[p & 127u], 1);
    }
    __syncthreads();
    // ---- phase 2: inclusive scan (Hillis-Steele over 128)
    if (t < GROWS) rofs[t] = cnt[t];
    __syncthreads();
    #pragma unroll
    for (int d = 1; d < GROWS; d <<= 1) {
        int tv = (t < GROWS && t >= d) ? rofs[t - d] : 0;
        __syncthreads();
        if (t < GROWS) rofs[t] += tv;
        __syncthreads();
    }
    if (t < GROWS) cur[t] = rofs[t] - cnt[t];
    __syncthreads();
    const int tot = rofs[GROWS - 1];

    if (tot <= CSR_CAP) {
        // ---- phase 3: position-scatter src ids into LDS CSR (L2-hot re-read)
        for (int i = beg + t; i < end; i += 512) {
            unsigned p = pairs[i];
            if ((p & 128u) == hbit) {
                int pos = atomicAdd(&cur[p & 127u], 1);
                csr[pos] = (int)(p >> 8);
            }
        }
        __syncthreads();
        // ---- phase 4: dual-row gather + softmax. Wave owns 16 rows as 8
        // pairs (rA, rB = rA+8); main loop keeps 16 gathers in flight.
        #pragma unroll 1
        for (int p8 = 0; p8 < GROWS / 16; ++p8) {
            const int rA = wave + 16 * p8;
            const int rB = rA + 8;
            const int eA = rofs[rA]; const int bAe = eA - cnt[rA];
            const int eB = rofs[rB]; const int bBe = eB - cnt[rB];
            float axA = 0.f, ayA = 0.f, axB = 0.f, ayB = 0.f;
            int iA = bAe, iB = bBe;
            // interleaved: 8 pairs from each row per iteration
            while (iA + 16 <= eA && iB + 16 <= eB) {
                int sA[8], sB[8];
                #pragma unroll
                for (int k = 0; k < 8; ++k) sA[k] = csr[iA + 2 * k + half];
                #pragma unroll
                for (int k = 0; k < 8; ++k) sB[k] = csr[iB + 2 * k + half];
                float2 fA[8], fB[8];
                #pragma unroll
                for (int k = 0; k < 8; ++k)
                    fA[k] = __half22float2(m2[(unsigned)(sA[k] * (OUT_DIM / 2) + c)]);
                #pragma unroll
                for (int k = 0; k < 8; ++k)
                    fB[k] = __half22float2(m2[(unsigned)(sB[k] * (OUT_DIM / 2) + c)]);
                #pragma unroll
                for (int k = 0; k < 8; ++k) {
                    axA += fA[k].x; ayA += fA[k].y;
                    axB += fB[k].x; ayB += fB[k].y;
                }
                iA += 16; iB += 16;
            }
            // finish row A
            for (; iA + 16 <= eA; iA += 16) {
                int s[8];
                #pragma unroll
                for (int k = 0; k < 8; ++k) s[k] = csr[iA + 2 * k + half];
                float2 f[8];
                #pragma unroll
                for (int k = 0; k < 8; ++k)
                    f[k] = __half22float2(m2[(unsigned)(s[k] * (OUT_DIM / 2) + c)]);
                #pragma unroll
                for (int k = 0; k < 8; ++k) { axA += f[k].x; ayA += f[k].y; }
            }
            for (int e = iA + half; e < eA; e += 2) {
                float2 f = __half22float2(m2[(unsigned)(csr[e] * (OUT_DIM / 2) + c)]);
                axA += f.x; ayA += f.y;
            }
            // finish row B
            for (; iB + 16 <= eB; iB += 16) {
                int s[8];
                #pragma unroll
                for (int k = 0; k < 8; ++k) s[k] = csr[iB + 2 * k + half];
                float2 f[8];
                #pragma unroll
                for (int k = 0; k < 8; ++k)
                    f[k] = __half22float2(m2[(unsigned)(s[k] * (OUT_DIM / 2) + c)]);
                #pragma unroll
                for (int k = 0; k < 8; ++k) { axB += f[k].x; ayB += f[k].y; }
            }
            for (int e = iB + half; e < eB; e += 2) {
                float2 f = __half22float2(m2[(unsigned)(csr[e] * (OUT_DIM / 2) + c)]);
                axB += f.x; ayB += f.y;
            }
            // combine halves + softmax + store, per row
            #pragma unroll
            for (int which = 0; which < 2; ++which) {
                float ax = which ? axB : axA;
                float ay = which ? ayB : ayA;
                const int r = which ? rB : rA;
                const int row = rowBase + r;
                ax += __shfl_xor(ax, 32, 64);
                ay += __shfl_xor(ay, 32, 64);
                float nd = rsqrtf(fmaxf((float)cnt[r], 1.0f));
                float x0 = ax * nd + bb.x;
                float x1 = ay * nd + bb.y;
                float mx = fmaxf(x0, x1);
                #pragma unroll
                for (int o = 16; o > 0; o >>= 1) mx = fmaxf(mx, __shfl_xor(mx, o, 64));
                float ex0 = expf(x0 - mx), ex1 = expf(x1 - mx);
                float sm = ex0 + ex1;
                #pragma unroll
                for (int o = 16; o > 0; o >>= 1) sm += __shfl_xor(sm, o, 64);
                float ls = logf(sm);
                if (half == 0 && row < n_nodes)
                    *(float2*)(out + (size_t)row * OUT_DIM + 2 * c) =
                        make_float2(x0 - mx - ls, x1 - mx - ls);
            }
        }
    } else {
        // ---- slow fallback (pathological half-bucket > CSR_CAP; never on
        // this input): every lane scans the whole parent segment for its rows.
        for (int r = wave; r < GROWS; r += 8) {
            const int row = rowBase + r;
            if (row >= n_nodes) continue;
            const unsigned match = (unsigned)(hsel * GROWS + r);
            float ax = 0.f, ay = 0.f;
            for (int e = beg; e < end; ++e) {
                unsigned p = pairs[e];
                if ((p & 255u) == match) {
                    float2 f = __half22float2(m2[(unsigned)((p >> 8) * (OUT_DIM / 2) + c)]);
                    ax += f.x; ay += f.y;
                }
            }
            float nd = rsqrtf(fmaxf((float)cnt[r], 1.0f));
            float x0 = ax * nd + bb.x;
            float x1 = ay * nd + bb.y;
            float mx = fmaxf(x0, x1);
            #pragma unroll
            for (int o = 16; o > 0; o >>= 1) mx = fmaxf(mx, __shfl_xor(mx, o, 64));
            float ex0 = expf(x0 - mx), ex1 = expf(x1 - mx);
            float sm = ex0 + ex1;
            #pragma unroll
            for (int o = 16; o > 0; o >>= 1) sm += __shfl_xor(sm, o, 64);
            float ls = logf(sm);
            if (half == 0)
                *(float2*)(out + (size_t)row * OUT_DIM + 2 * c) =
                    make_float2(x0 - mx - ls, x1 - mx - ls);
        }
    }
}

// ---------------------------------------------------------------------------
static inline size_t align16(size_t x) { return (x + 15) & ~(size_t)15; }

extern "C" void kernel_launch(void* const* d_in, const int* in_sizes, int n_in,
                              void* d_out, int out_size, void* d_ws, size_t ws_size,
                              hipStream_t stream) {
    const float* h = (const float*)d_in[0];
    const float* W = (const float*)d_in[1];
    const float* b = (const float*)d_in[2];
    const int* edges = (const int*)d_in[3];

    const int out_dim = in_sizes[2];            // 64
    const int in_dim  = in_sizes[1] / out_dim;  // 256
    const int n_nodes = in_sizes[0] / in_dim;   // 100000
    const int n_edges = in_sizes[3] / 2;        // 3200000

    const int* src = edges;
    const int* dst = edges + n_edges;

    float* out = (float*)d_out;

    const int nb = (n_nodes + BROWS - 1) / BROWS;  // 391 buckets

    // fixed bucket segment capacity: mean + 25% + 1024, then 1K-align.
    const int epb = (n_edges + nb - 1) / nb;
    const int cap = (epb + (epb >> 2) + 1023 + 1023) & ~1023;

    // workspace carve-up
    char* ws = (char*)d_ws;
    size_t off = 0;
    int* out_deg     = (int*)(ws + off); off = align16(off + (size_t)n_nodes * 4);
    int* dcursor     = (int*)(ws + off); off = align16(off + (size_t)nb * 4);
    int* scursor     = (int*)(ws + off); off = align16(off + (size_t)nb * 4);
    __half* m        = (__half*)(ws + off); off = align16(off + (size_t)n_nodes * OUT_DIM * 2);
    unsigned* pairs  = (unsigned*)(ws + off); off = align16(off + (size_t)nb * cap * 4);
    // sbytes aliases m's storage (scatter writes, count_src reads, both
    // before gemm writes m; serial stream ordering).
    unsigned char* sbytes = (unsigned char*)m;

    // zero both cursor arrays (contiguous)
    (void)hipMemsetAsync(dcursor, 0,
                         (size_t)((char*)(scursor + nb) - (char*)dcursor), stream);

    const int sc_blocks = (n_edges + SC_EDGES - 1) / SC_EDGES;

    scatter_pairs_kernel<<<sc_blocks, SC_THREADS, 0, stream>>>(
        src, dst, dcursor, scursor, pairs, sbytes, n_edges, nb, cap);
    count_src_kernel<<<nb, 256, 0, stream>>>(sbytes, scursor, out_deg, n_nodes, cap);

    gemm_kernel<<<(n_nodes + BM - 1) / BM, 256, 0, stream>>>(h, W, out_deg, m, n_nodes);

    bucket_gather_kernel<<<2 * nb, 512, 0, stream>>>(pairs, dcursor, m, b, out,
                                                     n_nodes, cap);
}